// Round 5
// baseline (281.425 us; speedup 1.0000x reference)
//
#include <hip/hip_runtime.h>
#include <hip/hip_bf16.h>
#include <math.h>

typedef unsigned short u16;
typedef unsigned int u32;
typedef unsigned char u8;

#define T_TOK 43904   // 128 windows * 343 tokens
#define NTOK 343
#define LOG2E 1.4426950408889634f
#define MASKV 144.26950408889634f   // 100 * log2(e)

typedef __attribute__((ext_vector_type(4))) float f32x4;
typedef __attribute__((ext_vector_type(8))) short s16x8;

__device__ __forceinline__ float bf2f(u32 v) { return __uint_as_float(v << 16); }
__device__ __forceinline__ u16 f2bf(float f) {
  u32 u = __float_as_uint(f);
  return (u16)((u + 0x7fffu + ((u >> 16) & 1u)) >> 16);
}

// ---- dual-dtype input loaders: f32!=0 -> data is fp32, else packed bf16 ----
__device__ __forceinline__ float ldf(const void* p, int f32, size_t i) {
  return f32 ? ((const float*)p)[i] : bf2f(((const u16*)p)[i]);
}
__device__ __forceinline__ float2 ld2(const void* p, int f32, size_t i) {  // i even
  if (f32) return *(const float2*)((const float*)p + i);
  u32 pk = *(const u32*)((const u16*)p + i);
  return make_float2(bf2f(pk & 0xffff), bf2f(pk >> 16));
}

// token index t (window-major) -> element offset of the (b,d,h,w) voxel in x/out
__device__ __forceinline__ size_t spatial_base(int t) {
  int win = t / 343, n = t - win * 343;
  int bb = win >> 6, wrem = win & 63;
  int wd = wrem >> 4, wh = (wrem >> 2) & 3, ww = wrem & 3;
  int td = n / 49; int r = n - td * 49; int th = r / 7; int tw = r - th * 7;
  int d0 = wd * 7 + td + 3; if (d0 >= 28) d0 -= 28;
  int h0 = wh * 7 + th + 3; if (h0 >= 28) h0 -= 28;
  int w0 = ww * 7 + tw + 3; if (w0 >= 28) w0 -= 28;
  return (size_t)(((bb * 28 + d0) * 28 + h0) * 28 + w0) * 96;
}

// shifted-window mask region id (exact reproduction of MONAI compute_mask)
__device__ __forceinline__ int zone3(int p) { return p < 21 ? 0 : (p < 25 ? 1 : 2); }
__device__ __forceinline__ int cid_of(int mw, int n) {
  int td = n / 49, rr = n - td * 49, th = rr / 7, tw = rr - th * 7;
  int d = (mw >> 4) * 7 + td, h = ((mw >> 2) & 3) * 7 + th, w = (mw & 3) * 7 + tw;
  return zone3(d) * 9 + zone3(h) * 3 + zone3(w);
}

// ---------------- dtype detector ----------------
__global__ __launch_bounds__(64) void detect_kernel(const u16* __restrict__ x, int* __restrict__ flag) {
  int lane = threadIdx.x;
  int bad = 0;
  #pragma unroll
  for (int q = 0; q < 8; q++) {
    u16 b = x[(lane * 8 + q) * 2];
    int e = (b >> 7) & 0xff;
    if (e >= 0x90) bad = 1;
  }
  unsigned long long m = __ballot(bad);
  if (lane == 0) *flag = (m != 0ull) ? 1 : 0;
}

// ---------------- weight conversion -> bf16 [n][k] concat ----------------
__global__ __launch_bounds__(256) void wconv_kernel(
    const void* __restrict__ w0, const void* __restrict__ w1,
    const void* __restrict__ w2, const void* __restrict__ w3,
    u16* __restrict__ out, const int* __restrict__ dflag) {
  int f32 = __builtin_amdgcn_readfirstlane(dflag[0]);
  int g = blockIdx.x * 256 + threadIdx.x;
  if (g >= 110592) return;
  float v;
  if (g < 27648)      v = ldf(w0, f32, g);
  else if (g < 36864) v = ldf(w1, f32, g - 27648);
  else if (g < 73728) v = ldf(w2, f32, g - 36864);
  else                v = ldf(w3, f32, g - 73728);
  out[g] = f2bf(v);
}

// ---------------- LN1 + shift + window partition gather ----------------
__global__ __launch_bounds__(256) void ln_gather_kernel(
    const void* __restrict__ x, const void* __restrict__ g, const void* __restrict__ b,
    u16* __restrict__ outw, const int* __restrict__ dflag) {
  int f32 = __builtin_amdgcn_readfirstlane(dflag[0]);
  int t = blockIdx.x * 4 + (threadIdx.x >> 6);
  int lane = threadIdx.x & 63;
  size_t base = spatial_base(t);
  int c = lane * 2;
  float vx = 0.f, vy = 0.f;
  if (c < 96) { float2 p = ld2(x, f32, base + c); vx = p.x; vy = p.y; }
  float s = vx + vy, ss = vx * vx + vy * vy;
  #pragma unroll
  for (int o = 1; o < 64; o <<= 1) { s += __shfl_xor(s, o); ss += __shfl_xor(ss, o); }
  float mean = s * (1.f / 96.f);
  float var = ss * (1.f / 96.f) - mean * mean;
  float rstd = rsqrtf(var + 1e-5f);
  if (c < 96) {
    float2 gp = ld2(g, f32, c), bp = ld2(b, f32, c);
    float y0 = (vx - mean) * rstd * gp.x + bp.x;
    float y1 = (vy - mean) * rstd * gp.y + bp.y;
    *(u32*)(outw + (size_t)t * 96 + c) = (u32)f2bf(y0) | ((u32)f2bf(y1) << 16);
  }
}

// ---------------- B3M: (bias + mask) * log2e, per window-class ----------------
// b3m[cls][head][row][col 352]; cls bit2=wd==3, bit1=wh==3, bit0=ww==3.
__global__ __launch_bounds__(256) void b3m_kernel(
    const void* __restrict__ bias_table, const int* __restrict__ rel,
    u16* __restrict__ b3m, const int* __restrict__ dflag) {
  int f32 = __builtin_amdgcn_readfirstlane(dflag[0]);
  int row = blockIdx.x;
  int by = blockIdx.y;            // cls*3 + head
  int cls = by / 3, head = by - cls * 3;
  int mw = ((cls & 4) ? 48 : 0) | ((cls & 2) ? 12 : 0) | ((cls & 1) ? 3 : 0);
  int cidq = cid_of(mw, row);
  for (int col = threadIdx.x; col < 352; col += 256) {
    float v = -MASKV;
    if (col < 343) {
      v = ldf(bias_table, f32, (size_t)rel[row * 343 + col] * 3 + head) * LOG2E;
      if (cid_of(mw, col) != cidq) v -= MASKV;
    }
    b3m[((size_t)by * 343 + row) * 352 + col] = f2bf(v);
  }
}

// ---------------- QKV MFMA GEMM -> planar [sel*3+head][tok][32] ----------------
// grid = (343, 3), block = 256. q-plane scaled by log2e/sqrt(32).
__global__ __launch_bounds__(256) void qkv_kernel(
    const u16* __restrict__ A, const u16* __restrict__ Wb, const void* __restrict__ bias,
    u16* __restrict__ outp, const int* __restrict__ dflag) {
  int f32 = __builtin_amdgcn_readfirstlane(dflag[0]);
  __shared__ alignas(16) u16 As[128 * 104];
  __shared__ alignas(16) u16 Ws[96 * 104];
  int tid = threadIdx.x;
  int m0 = blockIdx.x * 128, n0 = blockIdx.y * 96;
  int w = tid >> 6, lane = tid & 63, quad = lane >> 4, l16 = lane & 15;
  f32x4 acc[2][6];
  #pragma unroll
  for (int i = 0; i < 2; i++)
    #pragma unroll
    for (int j = 0; j < 6; j++) acc[i][j] = (f32x4){0.f, 0.f, 0.f, 0.f};
  for (int i = tid; i < 1536; i += 256) {
    int row = i / 12; int c = (i - row * 12) * 8;
    *(uint4*)&As[row * 104 + c] = *(const uint4*)(A + (size_t)(m0 + row) * 96 + c);
  }
  for (int i = tid; i < 1152; i += 256) {
    int row = i / 12; int c = (i - row * 12) * 8;
    *(uint4*)&Ws[row * 104 + c] = *(const uint4*)(Wb + (size_t)(n0 + row) * 96 + c);
  }
  __syncthreads();
  #pragma unroll
  for (int kc = 0; kc < 3; kc++) {
    s16x8 fa0 = *(const s16x8*)&As[(w * 32 + l16) * 104 + kc * 32 + quad * 8];
    s16x8 fa1 = *(const s16x8*)&As[(w * 32 + 16 + l16) * 104 + kc * 32 + quad * 8];
    #pragma unroll
    for (int j = 0; j < 6; j++) {
      s16x8 fb = *(const s16x8*)&Ws[(j * 16 + l16) * 104 + kc * 32 + quad * 8];
      acc[0][j] = __builtin_amdgcn_mfma_f32_16x16x32_bf16(fa0, fb, acc[0][j], 0, 0, 0);
      acc[1][j] = __builtin_amdgcn_mfma_f32_16x16x32_bf16(fa1, fb, acc[1][j], 0, 0, 0);
    }
  }
  #pragma unroll
  for (int i = 0; i < 2; i++) {
    #pragma unroll
    for (int r = 0; r < 4; r++) {
      int mm = m0 + w * 32 + i * 16 + quad * 4 + r;
      #pragma unroll
      for (int j = 0; j < 6; j++) {
        int nn = n0 + j * 16 + l16;
        float v = acc[i][j][r] + ldf(bias, f32, nn);
        int sel = nn / 96, hd = (nn - sel * 96) >> 5, cc = nn & 31;
        float scl = (sel == 0) ? 0.25504208f : 1.0f;   // log2e / sqrt(32)
        outp[((size_t)(sel * 3 + hd) * T_TOK + mm) * 32 + cc] = f2bf(v * scl);
      }
    }
  }
}

// ---------------- MFMA flash attention v3 ----------------
// grid = (3, 384), block = 512 (8 waves, 16 q-rows each; 128 q-rows/block).
__device__ __forceinline__ int vsw(int ch) { return ((ch >> 1) ^ (ch >> 3)) & 3; }

__global__ __launch_bounds__(512) void attn_mfma_kernel(
    const u16* __restrict__ qkv, const u16* __restrict__ b3m,
    u16* __restrict__ attnb) {
  __shared__ alignas(16) u16 Ks[352 * 32];   // idx = tok*32 + 8*((ch>>3)^(tok&3)) + (ch&7)
  __shared__ alignas(16) u16 Vt[32 * 352];   // idx = ch*352 + 8*((tok>>3)^vsw(ch)) + (tok&7)
  __shared__ alignas(16) u16 Ps[8][512];     // idx = q*32 + 8*((k32>>3)^swl(q)) + (k32&7)

  int tid = threadIdx.x;
  int wh = blockIdx.y;
  int head = wh % 3;
  int win = wh / 3;
  int mw = win & 63;
  int cls = (((mw >> 4) == 3) ? 4 : 0) | ((((mw >> 2) & 3) == 3) ? 2 : 0) | (((mw & 3) == 3) ? 1 : 0);
  int m0 = blockIdx.x * 128;
  size_t wbase = (size_t)win * NTOK;

  const u16* qplane = qkv + ((size_t)head * T_TOK + wbase) * 32;
  const u16* kplane = qkv + ((size_t)(3 + head) * T_TOK + wbase) * 32;
  const u16* vplane = qkv + ((size_t)(6 + head) * T_TOK + wbase) * 32;

  // stage K rows 0..351 (343+ zero)
  for (int i = tid; i < 1408; i += 512) {
    int tok = i >> 2, cb = i & 3;
    uint4 kv = make_uint4(0, 0, 0, 0);
    if (tok < 343) kv = *(const uint4*)(kplane + (size_t)tok * 32 + cb * 8);
    *(uint4*)&Ks[tok * 32 + 8 * (cb ^ (tok & 3))] = kv;
  }
  // stage V^T (token-pair u32 writes, conflict-free swizzle)
  for (int i = tid; i < 688; i += 512) {
    int p = i >> 2, cb = (i & 3) * 8;
    int t0 = 2 * p;
    uint4 v0 = *(const uint4*)(vplane + (size_t)t0 * 32 + cb);
    uint4 v1 = make_uint4(0, 0, 0, 0);
    if (t0 + 1 < 343) v1 = *(const uint4*)(vplane + (size_t)(t0 + 1) * 32 + cb);
    u32 a0[4] = {v0.x, v0.y, v0.z, v0.w};
    u32 a1[4] = {v1.x, v1.y, v1.z, v1.w};
    int blk = t0 >> 3, tin = (t0 & 7) >> 1;
    #pragma unroll
    for (int q = 0; q < 4; q++) {
      int ch0 = cb + 2 * q;
      u32 w0v = (a0[q] & 0xffffu) | ((a1[q] & 0xffffu) << 16);
      u32 w1v = (a0[q] >> 16) | (a1[q] & 0xffff0000u);
      ((u32*)Vt)[ch0 * 176 + 4 * (blk ^ vsw(ch0)) + tin] = w0v;
      ((u32*)Vt)[(ch0 + 1) * 176 + 4 * (blk ^ vsw(ch0 + 1)) + tin] = w1v;
    }
  }
  // zero V^T pad toks 344..351 (blk 43)
  if (tid < 256) {
    int ch = tid >> 3, j = tid & 7;
    Vt[ch * 352 + 8 * (43 ^ vsw(ch)) + j] = 0;
  }
  __syncthreads();

  int w = tid >> 6, lane = tid & 63, quad = lane >> 4, l16 = lane & 15;
  int qbase = m0 + w * 16;
  int qrow_l = qbase + l16;
  int qc = qrow_l < NTOK ? qrow_l : NTOK - 1;
  s16x8 fq = *(const s16x8*)(qplane + (size_t)qc * 32 + quad * 8);
  const u16* bmrow = b3m + ((size_t)(cls * 3 + head) * 343 + qc) * 352;
  int swl = (l16 ^ (l16 >> 2)) & 3;
  int vsw0 = vsw(l16), vsw1 = vsw(16 + l16);

  float lsum = 0.f;
  f32x4 o0 = {0.f, 0.f, 0.f, 0.f}, o1 = {0.f, 0.f, 0.f, 0.f};
  const f32x4 zz = {0.f, 0.f, 0.f, 0.f};

  for (int t32 = 0; t32 < 11; t32++) {
    #pragma unroll
    for (int h = 0; h < 2; h++) {
      int kb = t32 * 32 + h * 16;
      int ktok = kb + l16;
      s16x8 fk = *(const s16x8*)&Ks[ktok * 32 + 8 * (quad ^ (ktok & 3))];
      f32x4 st = __builtin_amdgcn_mfma_f32_16x16x32_bf16(fk, fq, zz, 0, 0, 0);
      uint2 bm = *(const uint2*)(bmrow + kb + quad * 4);
      float p0 = exp2f(st[0] + bf2f(bm.x & 0xffff));
      float p1 = exp2f(st[1] + bf2f(bm.x >> 16));
      float p2 = exp2f(st[2] + bf2f(bm.y & 0xffff));
      float p3 = exp2f(st[3] + bf2f(bm.y >> 16));
      lsum += (p0 + p1) + (p2 + p3);
      u32 pa = (__float_as_uint(p0) >> 16) | (__float_as_uint(p1) & 0xffff0000u);
      u32 pb = (__float_as_uint(p2) >> 16) | (__float_as_uint(p3) & 0xffff0000u);
      int blkp = h * 2 + (quad >> 1);
      *(uint2*)&Ps[w][l16 * 32 + 8 * (blkp ^ swl) + (quad & 1) * 4] = make_uint2(pa, pb);
    }
    // per-wave private Ps: wave-internal LDS ordering, no barrier
    s16x8 fp  = *(const s16x8*)&Ps[w][l16 * 32 + 8 * (quad ^ swl)];
    s16x8 fv0 = *(const s16x8*)&Vt[l16 * 352 + 8 * ((t32 * 4 + quad) ^ vsw0)];
    s16x8 fv1 = *(const s16x8*)&Vt[(16 + l16) * 352 + 8 * ((t32 * 4 + quad) ^ vsw1)];
    o0 = __builtin_amdgcn_mfma_f32_16x16x32_bf16(fp, fv0, o0, 0, 0, 0);
    o1 = __builtin_amdgcn_mfma_f32_16x16x32_bf16(fp, fv1, o1, 0, 0, 0);
  }

  lsum += __shfl_xor(lsum, 16);
  lsum += __shfl_xor(lsum, 32);
  #pragma unroll
  for (int r = 0; r < 4; r++) {
    int qrow = qbase + quad * 4 + r;
    float ls = __shfl(lsum, quad * 4 + r);
    if (qrow < NTOK) {
      float rs = 1.0f / ls;
      size_t ob = (wbase + qrow) * 96 + head * 32;
      attnb[ob + l16] = f2bf(o0[r] * rs);
      attnb[ob + 16 + l16] = f2bf(o1[r] * rs);
    }
  }
}

// ---------------- mega-fused MLP: proj+res+LN2+FC1+GELU+FC2+res+scatter ----------------
// grid = 686 (64 rows/block), block = 256 (4 waves x 16 rows).
// Round-0 structure + T14 async-STAGE split: each weight chunk is global-loaded
// to REGISTERS under the previous phase's MFMA+GELU compute, then written to LDS
// between the two barriers. Keeps LDS-read MFMA fragments identical; removes the
// L2 round-trip from the barrier-to-barrier critical path.
__global__ __launch_bounds__(256) void mlp_fused_kernel(
    const u16* __restrict__ attnb, const u16* __restrict__ wcat,
    const void* __restrict__ x, const void* __restrict__ b_proj,
    const void* __restrict__ g2, const void* __restrict__ b2,
    const void* __restrict__ b_fc1, const void* __restrict__ b_fc2,
    void* __restrict__ outp, const int* __restrict__ dflag) {
  int f32 = __builtin_amdgcn_readfirstlane(dflag[0]);
  __shared__ alignas(16) u16 As[64 * 104];
  __shared__ alignas(16) u16 As2[64 * 104];
  __shared__ alignas(16) u16 Ws[96 * 104];
  const u16* w_projb = wcat + 27648;
  const u16* w_fc1b  = wcat + 36864;
  const u16* w_fc2b  = wcat + 73728;
  int tid = threadIdx.x, m0 = blockIdx.x * 64;
  int w = tid >> 6, lane = tid & 63, quad = lane >> 4, l16 = lane & 15;

// issue 1152-u16 weight tile into 5 uint4 regs (threads 0..127 carry the 5th)
#define W_ISSUE(dst, src, rstrd, coff)                                        \
  _Pragma("unroll")                                                           \
  for (int k = 0; k < 5; k++) {                                               \
    int i_ = tid + 256 * k;                                                   \
    if (i_ < 1152) {                                                          \
      int rr_ = i_ / 12, cc_ = (i_ - rr_ * 12) * 8;                           \
      dst[k] = *(const uint4*)((src) + (size_t)rr_ * (rstrd) + (coff) + cc_); \
    }                                                                         \
  }
#define W_WRITE(src)                                                          \
  _Pragma("unroll")                                                           \
  for (int k = 0; k < 5; k++) {                                               \
    int i_ = tid + 256 * k;                                                   \
    if (i_ < 1152) {                                                          \
      int rr_ = i_ / 12, cc_ = (i_ - rr_ * 12) * 8;                           \
      *(uint4*)&Ws[rr_ * 104 + cc_] = src[k];                                 \
    }                                                                         \
  }

  // stage attn rows + w_proj (direct to LDS — nothing to hide under yet)
  for (int i = tid; i < 768; i += 256) {
    int row = i / 12, c = (i - row * 12) * 8;
    *(uint4*)&As[row * 104 + c] = *(const uint4*)(attnb + (size_t)(m0 + row) * 96 + c);
  }
  for (int i = tid; i < 1152; i += 256) {
    int row = i / 12, c = (i - row * 12) * 8;
    *(uint4*)&Ws[row * 104 + c] = *(const uint4*)(w_projb + (size_t)row * 96 + c);
  }
  uint4 rb[5], rb2[5];
  W_ISSUE(rb, w_fc1b, 96, 0);          // fc1[c=0] in flight under proj phase
  __syncthreads();

  f32x4 accp[6];
  #pragma unroll
  for (int j = 0; j < 6; j++) accp[j] = (f32x4){0.f, 0.f, 0.f, 0.f};
  #pragma unroll
  for (int kc = 0; kc < 3; kc++) {
    s16x8 fa = *(const s16x8*)&As[(w * 16 + l16) * 104 + kc * 32 + quad * 8];
    #pragma unroll
    for (int j = 0; j < 6; j++) {
      s16x8 fb = *(const s16x8*)&Ws[(j * 16 + l16) * 104 + kc * 32 + quad * 8];
      accp[j] = __builtin_amdgcn_mfma_f32_16x16x32_bf16(fa, fb, accp[j], 0, 0, 0);
    }
  }

  // epilogue 1: + b_proj + x -> rv ; LN2 -> As (own-wave slab, no barrier needed)
  float bp[6], gv[6], b2v[6];
  #pragma unroll
  for (int j = 0; j < 6; j++) {
    int nn = j * 16 + l16;
    bp[j] = ldf(b_proj, f32, nn); gv[j] = ldf(g2, f32, nn); b2v[j] = ldf(b2, f32, nn);
  }
  float rv[4][6];
  size_t sb[4];
  #pragma unroll
  for (int r = 0; r < 4; r++) {
    int mm = m0 + w * 16 + quad * 4 + r;
    sb[r] = spatial_base(mm);
    float s = 0.f, ss = 0.f;
    #pragma unroll
    for (int j = 0; j < 6; j++) {
      float v = accp[j][r] + bp[j] + ldf(x, f32, sb[r] + j * 16 + l16);
      rv[r][j] = v; s += v; ss += v * v;
    }
    #pragma unroll
    for (int o = 1; o < 16; o <<= 1) { s += __shfl_xor(s, o); ss += __shfl_xor(ss, o); }
    float mean = s * (1.f / 96.f);
    float var = ss * (1.f / 96.f) - mean * mean;
    float rstd = rsqrtf(var + 1e-5f);
    #pragma unroll
    for (int j = 0; j < 6; j++)
      As[(w * 16 + quad * 4 + r) * 104 + j * 16 + l16] = f2bf((rv[r][j] - mean) * rstd * gv[j] + b2v[j]);
  }

  __syncthreads();                     // all waves done reading Ws(proj)
  W_WRITE(rb);                         // Ws <- fc1[0]
  W_ISSUE(rb2, w_fc2b, 384, 0);        // fc2[c=0] in flight under fc1[0] phase
  __syncthreads();                     // Ws = fc1[0] visible

  f32x4 acc2[6];
  #pragma unroll
  for (int j = 0; j < 6; j++) acc2[j] = (f32x4){0.f, 0.f, 0.f, 0.f};
  for (int c = 0; c < 4; c++) {
    f32x4 a1[6];
    #pragma unroll
    for (int j = 0; j < 6; j++) a1[j] = (f32x4){0.f, 0.f, 0.f, 0.f};
    #pragma unroll
    for (int kc = 0; kc < 3; kc++) {
      s16x8 fa = *(const s16x8*)&As[(w * 16 + l16) * 104 + kc * 32 + quad * 8];
      #pragma unroll
      for (int j = 0; j < 6; j++) {
        s16x8 fb = *(const s16x8*)&Ws[(j * 16 + l16) * 104 + kc * 32 + quad * 8];
        a1[j] = __builtin_amdgcn_mfma_f32_16x16x32_bf16(fa, fb, a1[j], 0, 0, 0);
      }
    }
    #pragma unroll
    for (int j = 0; j < 6; j++) {
      float bf1 = ldf(b_fc1, f32, 96 * c + j * 16 + l16);
      #pragma unroll
      for (int r = 0; r < 4; r++) {
        float v = a1[j][r] + bf1;
        v = 0.5f * v * (1.0f + erff(v * 0.70710678118f));
        As2[(w * 16 + quad * 4 + r) * 104 + j * 16 + l16] = f2bf(v);
      }
    }
    __syncthreads();                   // all waves done reading Ws(fc1[c])
    W_WRITE(rb2);                      // Ws <- fc2[c]
    if (c < 3) W_ISSUE(rb, w_fc1b, 96, 9216 * (c + 1));   // fc1[c+1] in flight
    __syncthreads();                   // Ws = fc2[c] visible
    #pragma unroll
    for (int kc = 0; kc < 3; kc++) {
      s16x8 fa2 = *(const s16x8*)&As2[(w * 16 + l16) * 104 + kc * 32 + quad * 8];
      #pragma unroll
      for (int j = 0; j < 6; j++) {
        s16x8 fb = *(const s16x8*)&Ws[(j * 16 + l16) * 104 + kc * 32 + quad * 8];
        acc2[j] = __builtin_amdgcn_mfma_f32_16x16x32_bf16(fa2, fb, acc2[j], 0, 0, 0);
      }
    }
    if (c < 3) {
      __syncthreads();                 // all waves done reading Ws(fc2[c])
      W_WRITE(rb);                     // Ws <- fc1[c+1]
      W_ISSUE(rb2, w_fc2b, 384, 96 * (c + 1));            // fc2[c+1] in flight
      __syncthreads();                 // Ws = fc1[c+1] visible
    }
  }
#undef W_ISSUE
#undef W_WRITE

  // final: + b_fc2 + rv -> out at spatial location
  float bf2v[6];
  #pragma unroll
  for (int j = 0; j < 6; j++) bf2v[j] = ldf(b_fc2, f32, j * 16 + l16);
  #pragma unroll
  for (int r = 0; r < 4; r++) {
    #pragma unroll
    for (int j = 0; j < 6; j++) {
      float v = acc2[j][r] + bf2v[j] + rv[r][j];
      if (f32) ((float*)outp)[sb[r] + j * 16 + l16] = v;
      else     ((u16*)outp)[sb[r] + j * 16 + l16] = f2bf(v);
    }
  }
}

extern "C" void kernel_launch(void* const* d_in, const int* in_sizes, int n_in,
                              void* d_out, int out_size, void* d_ws, size_t ws_size,
                              hipStream_t stream) {
  (void)in_sizes; (void)n_in; (void)out_size; (void)ws_size;
  const void* x       = d_in[0];
  const void* g1      = d_in[2];
  const void* b1      = d_in[3];
  const void* w_qkv   = d_in[4];
  const void* b_qkv   = d_in[5];
  const void* bias_tb = d_in[6];
  const void* w_proj  = d_in[7];
  const void* b_proj  = d_in[8];
  const void* g2      = d_in[9];
  const void* b2      = d_in[10];
  const void* w_fc1   = d_in[11];
  const void* b_fc1   = d_in[12];
  const void* w_fc2   = d_in[13];
  const void* b_fc2   = d_in[14];
  const int* rel_idx  = (const int*)d_in[15];

  // workspace (~48.2 MB): dflag | winb 8.43M | qkvb 25.3M | attnb 8.43M | b3m 5.80M | wcat 0.22M
  char* ws = (char*)d_ws;
  int*  dflag = (int*)ws;
  u16*  winb  = (u16*)(ws + 256);
  u16*  qkvb  = (u16*)(ws + 8429824);
  u16*  attnb = (u16*)(ws + 33718528);
  u16*  b3mb  = (u16*)(ws + 42148096);
  u16*  wcat  = (u16*)(ws + 47943424);
  u16*  w_qkvb = wcat;

  detect_kernel<<<1, 64, 0, stream>>>((const u16*)x, dflag);
  wconv_kernel<<<432, 256, 0, stream>>>(w_qkv, w_proj, w_fc1, w_fc2, wcat, dflag);
  b3m_kernel<<<dim3(343, 24), 256, 0, stream>>>(bias_tb, rel_idx, b3mb, dflag);
  // 1. LN1 + shift + window partition
  ln_gather_kernel<<<T_TOK / 4, 256, 0, stream>>>(x, g1, b1, winb, dflag);
  // 2. QKV GEMM -> planar qkv (q pre-scaled by log2e/sqrt(32))
  qkv_kernel<<<dim3(343, 3), 256, 0, stream>>>(winb, w_qkvb, b_qkv, qkvb, dflag);
  // 3. flash attention -> attnb
  attn_mfma_kernel<<<dim3(3, 384), 512, 0, stream>>>(qkvb, b3mb, attnb);
  // 4. proj + residual + LN2 + FC1 + GELU + FC2 + residual + scatter -> d_out
  mlp_fused_kernel<<<686, 256, 0, stream>>>(attnb, wcat, x, b_proj, g2, b2,
                                            b_fc1, b_fc2, d_out, dflag);
}

// Round 6
// 235.841 us; speedup vs baseline: 1.1933x; 1.1933x over previous
//
#include <hip/hip_runtime.h>
#include <hip/hip_bf16.h>
#include <math.h>

typedef unsigned short u16;
typedef unsigned int u32;
typedef unsigned char u8;

#define T_TOK 43904   // 128 windows * 343 tokens
#define NTOK 343
#define LOG2E 1.4426950408889634f
#define MASKV 144.26950408889634f   // 100 * log2(e)

typedef __attribute__((ext_vector_type(4))) float f32x4;
typedef __attribute__((ext_vector_type(8))) short s16x8;

__device__ __forceinline__ float bf2f(u32 v) { return __uint_as_float(v << 16); }
__device__ __forceinline__ u16 f2bf(float f) {
  u32 u = __float_as_uint(f);
  return (u16)((u + 0x7fffu + ((u >> 16) & 1u)) >> 16);
}

// ---- dual-dtype input loaders: f32!=0 -> data is fp32, else packed bf16 ----
__device__ __forceinline__ float ldf(const void* p, int f32, size_t i) {
  return f32 ? ((const float*)p)[i] : bf2f(((const u16*)p)[i]);
}
__device__ __forceinline__ float2 ld2(const void* p, int f32, size_t i) {  // i even
  if (f32) return *(const float2*)((const float*)p + i);
  u32 pk = *(const u32*)((const u16*)p + i);
  return make_float2(bf2f(pk & 0xffff), bf2f(pk >> 16));
}

// token index t (window-major) -> element offset of the (b,d,h,w) voxel in x/out
__device__ __forceinline__ size_t spatial_base(int t) {
  int win = t / 343, n = t - win * 343;
  int bb = win >> 6, wrem = win & 63;
  int wd = wrem >> 4, wh = (wrem >> 2) & 3, ww = wrem & 3;
  int td = n / 49; int r = n - td * 49; int th = r / 7; int tw = r - th * 7;
  int d0 = wd * 7 + td + 3; if (d0 >= 28) d0 -= 28;
  int h0 = wh * 7 + th + 3; if (h0 >= 28) h0 -= 28;
  int w0 = ww * 7 + tw + 3; if (w0 >= 28) w0 -= 28;
  return (size_t)(((bb * 28 + d0) * 28 + h0) * 28 + w0) * 96;
}

// shifted-window mask region id (exact reproduction of MONAI compute_mask)
__device__ __forceinline__ int zone3(int p) { return p < 21 ? 0 : (p < 25 ? 1 : 2); }
__device__ __forceinline__ int cid_of(int mw, int n) {
  int td = n / 49, rr = n - td * 49, th = rr / 7, tw = rr - th * 7;
  int d = (mw >> 4) * 7 + td, h = ((mw >> 2) & 3) * 7 + th, w = (mw & 3) * 7 + tw;
  return zone3(d) * 9 + zone3(h) * 3 + zone3(w);
}

// ---------------- merged prep: self-detect + wconv + b3m + ln_gather ----------------
// grid = 19640 flat blocks, 256 threads:
//   [0, 432)      weight conversion -> wcat
//   [432, 8664)   b3m (flat = row + 343*by)
//   [8664, 19640) LN1 + shift + window gather -> winb (4 tokens/block)
// Each block self-detects input dtype (64-lane ballot on x, identical to the old
// detect_kernel) -> no serialized 1-block detect launch, no cross-kernel dep.
__global__ __launch_bounds__(256) void prep_kernel(
    const u16* __restrict__ xu,
    const void* __restrict__ x, const void* __restrict__ g1, const void* __restrict__ b1,
    const void* __restrict__ w_qkv, const void* __restrict__ w_proj,
    const void* __restrict__ w_fc1, const void* __restrict__ w_fc2,
    const void* __restrict__ bias_table, const int* __restrict__ rel,
    u16* __restrict__ wcat, u16* __restrict__ b3m, u16* __restrict__ winb,
    int* __restrict__ dflag) {
  __shared__ int sflag;
  int tid = threadIdx.x;
  if (tid < 64) {
    int bad = 0;
    #pragma unroll
    for (int q = 0; q < 8; q++) {
      u16 bb = xu[(tid * 8 + q) * 2];
      int e = (bb >> 7) & 0xff;
      if (e >= 0x90) bad = 1;
    }
    unsigned long long m = __ballot(bad);
    if (tid == 0) sflag = (m != 0ull) ? 1 : 0;
  }
  __syncthreads();
  int f32 = __builtin_amdgcn_readfirstlane(sflag);
  int b = blockIdx.x;
  if (b == 0 && tid == 0) *dflag = f32;     // consumed by qkv/mlp (later launches)

  if (b < 432) {
    // ---- weight conversion -> bf16 [n][k] concat ----
    int g = b * 256 + tid;
    if (g >= 110592) return;
    float v;
    if (g < 27648)      v = ldf(w_qkv, f32, g);
    else if (g < 36864) v = ldf(w_proj, f32, g - 27648);
    else if (g < 73728) v = ldf(w_fc1, f32, g - 36864);
    else                v = ldf(w_fc2, f32, g - 73728);
    wcat[g] = f2bf(v);
  } else if (b < 8664) {
    // ---- B3M: (bias + mask) * log2e, per window-class ----
    int idx = b - 432;
    int by = idx / 343, row = idx - by * 343;     // by = cls*3 + head
    int cls = by / 3, head = by - cls * 3;
    int mw = ((cls & 4) ? 48 : 0) | ((cls & 2) ? 12 : 0) | ((cls & 1) ? 3 : 0);
    int cidq = cid_of(mw, row);
    for (int col = tid; col < 352; col += 256) {
      float v = -MASKV;
      if (col < 343) {
        v = ldf(bias_table, f32, (size_t)rel[row * 343 + col] * 3 + head) * LOG2E;
        if (cid_of(mw, col) != cidq) v -= MASKV;
      }
      b3m[((size_t)by * 343 + row) * 352 + col] = f2bf(v);
    }
  } else {
    // ---- LN1 + shift + window partition gather ----
    int t = (b - 8664) * 4 + (tid >> 6);
    int lane = tid & 63;
    size_t base = spatial_base(t);
    int c = lane * 2;
    float vx = 0.f, vy = 0.f;
    if (c < 96) { float2 p = ld2(x, f32, base + c); vx = p.x; vy = p.y; }
    float s = vx + vy, ss = vx * vx + vy * vy;
    #pragma unroll
    for (int o = 1; o < 64; o <<= 1) { s += __shfl_xor(s, o); ss += __shfl_xor(ss, o); }
    float mean = s * (1.f / 96.f);
    float var = ss * (1.f / 96.f) - mean * mean;
    float rstd = rsqrtf(var + 1e-5f);
    if (c < 96) {
      float2 gp = ld2(g1, f32, c), bp = ld2(b1, f32, c);
      float y0 = (vx - mean) * rstd * gp.x + bp.x;
      float y1 = (vy - mean) * rstd * gp.y + bp.y;
      *(u32*)(winb + (size_t)t * 96 + c) = (u32)f2bf(y0) | ((u32)f2bf(y1) << 16);
    }
  }
}

// ---------------- QKV MFMA GEMM -> planar [sel*3+head][tok][32] ----------------
// grid = (343, 3), block = 256. q-plane scaled by log2e/sqrt(32).
__global__ __launch_bounds__(256) void qkv_kernel(
    const u16* __restrict__ A, const u16* __restrict__ Wb, const void* __restrict__ bias,
    u16* __restrict__ outp, const int* __restrict__ dflag) {
  int f32 = __builtin_amdgcn_readfirstlane(dflag[0]);
  __shared__ alignas(16) u16 As[128 * 104];
  __shared__ alignas(16) u16 Ws[96 * 104];
  int tid = threadIdx.x;
  int m0 = blockIdx.x * 128, n0 = blockIdx.y * 96;
  int w = tid >> 6, lane = tid & 63, quad = lane >> 4, l16 = lane & 15;
  f32x4 acc[2][6];
  #pragma unroll
  for (int i = 0; i < 2; i++)
    #pragma unroll
    for (int j = 0; j < 6; j++) acc[i][j] = (f32x4){0.f, 0.f, 0.f, 0.f};
  for (int i = tid; i < 1536; i += 256) {
    int row = i / 12; int c = (i - row * 12) * 8;
    *(uint4*)&As[row * 104 + c] = *(const uint4*)(A + (size_t)(m0 + row) * 96 + c);
  }
  for (int i = tid; i < 1152; i += 256) {
    int row = i / 12; int c = (i - row * 12) * 8;
    *(uint4*)&Ws[row * 104 + c] = *(const uint4*)(Wb + (size_t)(n0 + row) * 96 + c);
  }
  __syncthreads();
  #pragma unroll
  for (int kc = 0; kc < 3; kc++) {
    s16x8 fa0 = *(const s16x8*)&As[(w * 32 + l16) * 104 + kc * 32 + quad * 8];
    s16x8 fa1 = *(const s16x8*)&As[(w * 32 + 16 + l16) * 104 + kc * 32 + quad * 8];
    #pragma unroll
    for (int j = 0; j < 6; j++) {
      s16x8 fb = *(const s16x8*)&Ws[(j * 16 + l16) * 104 + kc * 32 + quad * 8];
      acc[0][j] = __builtin_amdgcn_mfma_f32_16x16x32_bf16(fa0, fb, acc[0][j], 0, 0, 0);
      acc[1][j] = __builtin_amdgcn_mfma_f32_16x16x32_bf16(fa1, fb, acc[1][j], 0, 0, 0);
    }
  }
  #pragma unroll
  for (int i = 0; i < 2; i++) {
    #pragma unroll
    for (int r = 0; r < 4; r++) {
      int mm = m0 + w * 32 + i * 16 + quad * 4 + r;
      #pragma unroll
      for (int j = 0; j < 6; j++) {
        int nn = n0 + j * 16 + l16;
        float v = acc[i][j][r] + ldf(bias, f32, nn);
        int sel = nn / 96, hd = (nn - sel * 96) >> 5, cc = nn & 31;
        float scl = (sel == 0) ? 0.25504208f : 1.0f;   // log2e / sqrt(32)
        outp[((size_t)(sel * 3 + hd) * T_TOK + mm) * 32 + cc] = f2bf(v * scl);
      }
    }
  }
}

// ---------------- MFMA flash attention v3 ----------------
// grid = (3, 384), block = 512 (8 waves, 16 q-rows each; 128 q-rows/block).
__device__ __forceinline__ int vsw(int ch) { return ((ch >> 1) ^ (ch >> 3)) & 3; }

__global__ __launch_bounds__(512) void attn_mfma_kernel(
    const u16* __restrict__ qkv, const u16* __restrict__ b3m,
    u16* __restrict__ attnb) {
  __shared__ alignas(16) u16 Ks[352 * 32];   // idx = tok*32 + 8*((ch>>3)^(tok&3)) + (ch&7)
  __shared__ alignas(16) u16 Vt[32 * 352];   // idx = ch*352 + 8*((tok>>3)^vsw(ch)) + (tok&7)
  __shared__ alignas(16) u16 Ps[8][512];     // idx = q*32 + 8*((k32>>3)^swl(q)) + (k32&7)

  int tid = threadIdx.x;
  int wh = blockIdx.y;
  int head = wh % 3;
  int win = wh / 3;
  int mw = win & 63;
  int cls = (((mw >> 4) == 3) ? 4 : 0) | ((((mw >> 2) & 3) == 3) ? 2 : 0) | (((mw & 3) == 3) ? 1 : 0);
  int m0 = blockIdx.x * 128;
  size_t wbase = (size_t)win * NTOK;

  const u16* qplane = qkv + ((size_t)head * T_TOK + wbase) * 32;
  const u16* kplane = qkv + ((size_t)(3 + head) * T_TOK + wbase) * 32;
  const u16* vplane = qkv + ((size_t)(6 + head) * T_TOK + wbase) * 32;

  // stage K rows 0..351 (343+ zero)
  for (int i = tid; i < 1408; i += 512) {
    int tok = i >> 2, cb = i & 3;
    uint4 kv = make_uint4(0, 0, 0, 0);
    if (tok < 343) kv = *(const uint4*)(kplane + (size_t)tok * 32 + cb * 8);
    *(uint4*)&Ks[tok * 32 + 8 * (cb ^ (tok & 3))] = kv;
  }
  // stage V^T (token-pair u32 writes, conflict-free swizzle)
  for (int i = tid; i < 688; i += 512) {
    int p = i >> 2, cb = (i & 3) * 8;
    int t0 = 2 * p;
    uint4 v0 = *(const uint4*)(vplane + (size_t)t0 * 32 + cb);
    uint4 v1 = make_uint4(0, 0, 0, 0);
    if (t0 + 1 < 343) v1 = *(const uint4*)(vplane + (size_t)(t0 + 1) * 32 + cb);
    u32 a0[4] = {v0.x, v0.y, v0.z, v0.w};
    u32 a1[4] = {v1.x, v1.y, v1.z, v1.w};
    int blk = t0 >> 3, tin = (t0 & 7) >> 1;
    #pragma unroll
    for (int q = 0; q < 4; q++) {
      int ch0 = cb + 2 * q;
      u32 w0v = (a0[q] & 0xffffu) | ((a1[q] & 0xffffu) << 16);
      u32 w1v = (a0[q] >> 16) | (a1[q] & 0xffff0000u);
      ((u32*)Vt)[ch0 * 176 + 4 * (blk ^ vsw(ch0)) + tin] = w0v;
      ((u32*)Vt)[(ch0 + 1) * 176 + 4 * (blk ^ vsw(ch0 + 1)) + tin] = w1v;
    }
  }
  // zero V^T pad toks 344..351 (blk 43)
  if (tid < 256) {
    int ch = tid >> 3, j = tid & 7;
    Vt[ch * 352 + 8 * (43 ^ vsw(ch)) + j] = 0;
  }
  __syncthreads();

  int w = tid >> 6, lane = tid & 63, quad = lane >> 4, l16 = lane & 15;
  int qbase = m0 + w * 16;
  int qrow_l = qbase + l16;
  int qc = qrow_l < NTOK ? qrow_l : NTOK - 1;
  s16x8 fq = *(const s16x8*)(qplane + (size_t)qc * 32 + quad * 8);
  const u16* bmrow = b3m + ((size_t)(cls * 3 + head) * 343 + qc) * 352;
  int swl = (l16 ^ (l16 >> 2)) & 3;
  int vsw0 = vsw(l16), vsw1 = vsw(16 + l16);

  float lsum = 0.f;
  f32x4 o0 = {0.f, 0.f, 0.f, 0.f}, o1 = {0.f, 0.f, 0.f, 0.f};
  const f32x4 zz = {0.f, 0.f, 0.f, 0.f};

  for (int t32 = 0; t32 < 11; t32++) {
    #pragma unroll
    for (int h = 0; h < 2; h++) {
      int kb = t32 * 32 + h * 16;
      int ktok = kb + l16;
      s16x8 fk = *(const s16x8*)&Ks[ktok * 32 + 8 * (quad ^ (ktok & 3))];
      f32x4 st = __builtin_amdgcn_mfma_f32_16x16x32_bf16(fk, fq, zz, 0, 0, 0);
      uint2 bm = *(const uint2*)(bmrow + kb + quad * 4);
      float p0 = exp2f(st[0] + bf2f(bm.x & 0xffff));
      float p1 = exp2f(st[1] + bf2f(bm.x >> 16));
      float p2 = exp2f(st[2] + bf2f(bm.y & 0xffff));
      float p3 = exp2f(st[3] + bf2f(bm.y >> 16));
      lsum += (p0 + p1) + (p2 + p3);
      u32 pa = (__float_as_uint(p0) >> 16) | (__float_as_uint(p1) & 0xffff0000u);
      u32 pb = (__float_as_uint(p2) >> 16) | (__float_as_uint(p3) & 0xffff0000u);
      int blkp = h * 2 + (quad >> 1);
      *(uint2*)&Ps[w][l16 * 32 + 8 * (blkp ^ swl) + (quad & 1) * 4] = make_uint2(pa, pb);
    }
    // per-wave private Ps: wave-internal LDS ordering, no barrier
    s16x8 fp  = *(const s16x8*)&Ps[w][l16 * 32 + 8 * (quad ^ swl)];
    s16x8 fv0 = *(const s16x8*)&Vt[l16 * 352 + 8 * ((t32 * 4 + quad) ^ vsw0)];
    s16x8 fv1 = *(const s16x8*)&Vt[(16 + l16) * 352 + 8 * ((t32 * 4 + quad) ^ vsw1)];
    o0 = __builtin_amdgcn_mfma_f32_16x16x32_bf16(fp, fv0, o0, 0, 0, 0);
    o1 = __builtin_amdgcn_mfma_f32_16x16x32_bf16(fp, fv1, o1, 0, 0, 0);
  }

  lsum += __shfl_xor(lsum, 16);
  lsum += __shfl_xor(lsum, 32);
  #pragma unroll
  for (int r = 0; r < 4; r++) {
    int qrow = qbase + quad * 4 + r;
    float ls = __shfl(lsum, quad * 4 + r);
    if (qrow < NTOK) {
      float rs = 1.0f / ls;
      size_t ob = (wbase + qrow) * 96 + head * 32;
      attnb[ob + l16] = f2bf(o0[r] * rs);
      attnb[ob + 16 + l16] = f2bf(o1[r] * rs);
    }
  }
}

// ---------------- mega-fused MLP: proj+res+LN2+FC1+GELU+FC2+res+scatter ----------------
// grid = 686 (64 rows/block), block = 256 (4 waves x 16 rows).
// Byte-exact round-0 structure (fastest measured: 42.6 us).
__global__ __launch_bounds__(256) void mlp_fused_kernel(
    const u16* __restrict__ attnb, const u16* __restrict__ wcat,
    const void* __restrict__ x, const void* __restrict__ b_proj,
    const void* __restrict__ g2, const void* __restrict__ b2,
    const void* __restrict__ b_fc1, const void* __restrict__ b_fc2,
    void* __restrict__ outp, const int* __restrict__ dflag) {
  int f32 = __builtin_amdgcn_readfirstlane(dflag[0]);
  __shared__ alignas(16) u16 As[64 * 104];
  __shared__ alignas(16) u16 As2[64 * 104];
  __shared__ alignas(16) u16 Ws[96 * 104];
  const u16* w_projb = wcat + 27648;
  const u16* w_fc1b  = wcat + 36864;
  const u16* w_fc2b  = wcat + 73728;
  int tid = threadIdx.x, m0 = blockIdx.x * 64;
  int w = tid >> 6, lane = tid & 63, quad = lane >> 4, l16 = lane & 15;

  // stage attn rows + w_proj
  for (int i = tid; i < 768; i += 256) {
    int row = i / 12, c = (i - row * 12) * 8;
    *(uint4*)&As[row * 104 + c] = *(const uint4*)(attnb + (size_t)(m0 + row) * 96 + c);
  }
  for (int i = tid; i < 1152; i += 256) {
    int row = i / 12, c = (i - row * 12) * 8;
    *(uint4*)&Ws[row * 104 + c] = *(const uint4*)(w_projb + row * 96 + c);
  }
  __syncthreads();
  f32x4 accp[6];
  #pragma unroll
  for (int j = 0; j < 6; j++) accp[j] = (f32x4){0.f, 0.f, 0.f, 0.f};
  #pragma unroll
  for (int kc = 0; kc < 3; kc++) {
    s16x8 fa = *(const s16x8*)&As[(w * 16 + l16) * 104 + kc * 32 + quad * 8];
    #pragma unroll
    for (int j = 0; j < 6; j++) {
      s16x8 fb = *(const s16x8*)&Ws[(j * 16 + l16) * 104 + kc * 32 + quad * 8];
      accp[j] = __builtin_amdgcn_mfma_f32_16x16x32_bf16(fa, fb, accp[j], 0, 0, 0);
    }
  }
  __syncthreads();   // all waves done reading As/Ws before overwrite

  // epilogue 1: + b_proj + x -> rv ; LN2 -> As (own-wave slab)
  float bp[6], gv[6], b2v[6];
  #pragma unroll
  for (int j = 0; j < 6; j++) {
    int nn = j * 16 + l16;
    bp[j] = ldf(b_proj, f32, nn); gv[j] = ldf(g2, f32, nn); b2v[j] = ldf(b2, f32, nn);
  }
  float rv[4][6];
  size_t sb[4];
  #pragma unroll
  for (int r = 0; r < 4; r++) {
    int mm = m0 + w * 16 + quad * 4 + r;
    sb[r] = spatial_base(mm);
    float s = 0.f, ss = 0.f;
    #pragma unroll
    for (int j = 0; j < 6; j++) {
      float v = accp[j][r] + bp[j] + ldf(x, f32, sb[r] + j * 16 + l16);
      rv[r][j] = v; s += v; ss += v * v;
    }
    #pragma unroll
    for (int o = 1; o < 16; o <<= 1) { s += __shfl_xor(s, o); ss += __shfl_xor(ss, o); }
    float mean = s * (1.f / 96.f);
    float var = ss * (1.f / 96.f) - mean * mean;
    float rstd = rsqrtf(var + 1e-5f);
    #pragma unroll
    for (int j = 0; j < 6; j++)
      As[(w * 16 + quad * 4 + r) * 104 + j * 16 + l16] = f2bf((rv[r][j] - mean) * rstd * gv[j] + b2v[j]);
  }

  f32x4 acc2[6];
  #pragma unroll
  for (int j = 0; j < 6; j++) acc2[j] = (f32x4){0.f, 0.f, 0.f, 0.f};
  for (int c = 0; c < 4; c++) {
    __syncthreads();
    for (int i = tid; i < 1152; i += 256) {
      int row = i / 12, cc = (i - row * 12) * 8;
      *(uint4*)&Ws[row * 104 + cc] = *(const uint4*)(w_fc1b + (size_t)(96 * c + row) * 96 + cc);
    }
    __syncthreads();
    f32x4 a1[6];
    #pragma unroll
    for (int j = 0; j < 6; j++) a1[j] = (f32x4){0.f, 0.f, 0.f, 0.f};
    #pragma unroll
    for (int kc = 0; kc < 3; kc++) {
      s16x8 fa = *(const s16x8*)&As[(w * 16 + l16) * 104 + kc * 32 + quad * 8];
      #pragma unroll
      for (int j = 0; j < 6; j++) {
        s16x8 fb = *(const s16x8*)&Ws[(j * 16 + l16) * 104 + kc * 32 + quad * 8];
        a1[j] = __builtin_amdgcn_mfma_f32_16x16x32_bf16(fa, fb, a1[j], 0, 0, 0);
      }
    }
    #pragma unroll
    for (int j = 0; j < 6; j++) {
      float bf1 = ldf(b_fc1, f32, 96 * c + j * 16 + l16);
      #pragma unroll
      for (int r = 0; r < 4; r++) {
        float v = a1[j][r] + bf1;
        v = 0.5f * v * (1.0f + erff(v * 0.70710678118f));
        As2[(w * 16 + quad * 4 + r) * 104 + j * 16 + l16] = f2bf(v);
      }
    }
    __syncthreads();
    for (int i = tid; i < 1152; i += 256) {
      int row = i / 12, cc = (i - row * 12) * 8;
      *(uint4*)&Ws[row * 104 + cc] = *(const uint4*)(w_fc2b + (size_t)row * 384 + 96 * c + cc);
    }
    __syncthreads();
    #pragma unroll
    for (int kc = 0; kc < 3; kc++) {
      s16x8 fa2 = *(const s16x8*)&As2[(w * 16 + l16) * 104 + kc * 32 + quad * 8];
      #pragma unroll
      for (int j = 0; j < 6; j++) {
        s16x8 fb = *(const s16x8*)&Ws[(j * 16 + l16) * 104 + kc * 32 + quad * 8];
        acc2[j] = __builtin_amdgcn_mfma_f32_16x16x32_bf16(fa2, fb, acc2[j], 0, 0, 0);
      }
    }
  }
  // final: + b_fc2 + rv -> out at spatial location
  float bf2v[6];
  #pragma unroll
  for (int j = 0; j < 6; j++) bf2v[j] = ldf(b_fc2, f32, j * 16 + l16);
  #pragma unroll
  for (int r = 0; r < 4; r++) {
    #pragma unroll
    for (int j = 0; j < 6; j++) {
      float v = acc2[j][r] + bf2v[j] + rv[r][j];
      if (f32) ((float*)outp)[sb[r] + j * 16 + l16] = v;
      else     ((u16*)outp)[sb[r] + j * 16 + l16] = f2bf(v);
    }
  }
}

extern "C" void kernel_launch(void* const* d_in, const int* in_sizes, int n_in,
                              void* d_out, int out_size, void* d_ws, size_t ws_size,
                              hipStream_t stream) {
  (void)in_sizes; (void)n_in; (void)out_size; (void)ws_size;
  const void* x       = d_in[0];
  const void* g1      = d_in[2];
  const void* b1      = d_in[3];
  const void* w_qkv   = d_in[4];
  const void* b_qkv   = d_in[5];
  const void* bias_tb = d_in[6];
  const void* w_proj  = d_in[7];
  const void* b_proj  = d_in[8];
  const void* g2      = d_in[9];
  const void* b2      = d_in[10];
  const void* w_fc1   = d_in[11];
  const void* b_fc1   = d_in[12];
  const void* w_fc2   = d_in[13];
  const void* b_fc2   = d_in[14];
  const int* rel_idx  = (const int*)d_in[15];

  // workspace (~48.2 MB): dflag | winb 8.43M | qkvb 25.3M | attnb 8.43M | b3m 5.80M | wcat 0.22M
  char* ws = (char*)d_ws;
  int*  dflag = (int*)ws;
  u16*  winb  = (u16*)(ws + 256);
  u16*  qkvb  = (u16*)(ws + 8429824);
  u16*  attnb = (u16*)(ws + 33718528);
  u16*  b3mb  = (u16*)(ws + 42148096);
  u16*  wcat  = (u16*)(ws + 47943424);
  u16*  w_qkvb = wcat;

  // 0. merged prep: self-detect + wconv + b3m + LN1/shift/gather (one launch)
  prep_kernel<<<19640, 256, 0, stream>>>(
      (const u16*)x, x, g1, b1, w_qkv, w_proj, w_fc1, w_fc2,
      bias_tb, rel_idx, wcat, b3mb, winb, dflag);
  // 1. QKV GEMM -> planar qkv (q pre-scaled by log2e/sqrt(32))
  qkv_kernel<<<dim3(343, 3), 256, 0, stream>>>(winb, w_qkvb, b_qkv, qkvb, dflag);
  // 2. flash attention -> attnb
  attn_mfma_kernel<<<dim3(3, 384), 512, 0, stream>>>(qkvb, b3mb, attnb);
  // 3. proj + residual + LN2 + FC1 + GELU + FC2 + residual + scatter -> d_out
  mlp_fused_kernel<<<686, 256, 0, stream>>>(attnb, wcat, x, b_proj, g2, b2,
                                            b_fc1, b_fc2, d_out, dflag);
}

// Round 7
// 225.367 us; speedup vs baseline: 1.2487x; 1.0465x over previous
//
#include <hip/hip_runtime.h>
#include <hip/hip_bf16.h>
#include <math.h>

typedef unsigned short u16;
typedef unsigned int u32;
typedef unsigned char u8;

#define T_TOK 43904   // 128 windows * 343 tokens
#define NTOK 343
#define LOG2E 1.4426950408889634f
#define MASKV 144.26950408889634f   // 100 * log2(e)

typedef __attribute__((ext_vector_type(4))) float f32x4;
typedef __attribute__((ext_vector_type(8))) short s16x8;

__device__ __forceinline__ float bf2f(u32 v) { return __uint_as_float(v << 16); }
__device__ __forceinline__ u16 f2bf(float f) {
  u32 u = __float_as_uint(f);
  return (u16)((u + 0x7fffu + ((u >> 16) & 1u)) >> 16);
}

// ---- dual-dtype input loaders: f32!=0 -> data is fp32, else packed bf16 ----
__device__ __forceinline__ float ldf(const void* p, int f32, size_t i) {
  return f32 ? ((const float*)p)[i] : bf2f(((const u16*)p)[i]);
}
__device__ __forceinline__ float2 ld2(const void* p, int f32, size_t i) {  // i even
  if (f32) return *(const float2*)((const float*)p + i);
  u32 pk = *(const u32*)((const u16*)p + i);
  return make_float2(bf2f(pk & 0xffff), bf2f(pk >> 16));
}

// token index t (window-major) -> element offset of the (b,d,h,w) voxel in x/out
__device__ __forceinline__ size_t spatial_base(int t) {
  int win = t / 343, n = t - win * 343;
  int bb = win >> 6, wrem = win & 63;
  int wd = wrem >> 4, wh = (wrem >> 2) & 3, ww = wrem & 3;
  int td = n / 49; int r = n - td * 49; int th = r / 7; int tw = r - th * 7;
  int d0 = wd * 7 + td + 3; if (d0 >= 28) d0 -= 28;
  int h0 = wh * 7 + th + 3; if (h0 >= 28) h0 -= 28;
  int w0 = ww * 7 + tw + 3; if (w0 >= 28) w0 -= 28;
  return (size_t)(((bb * 28 + d0) * 28 + h0) * 28 + w0) * 96;
}

// shifted-window mask region id (exact reproduction of MONAI compute_mask)
__device__ __forceinline__ int zone3(int p) { return p < 21 ? 0 : (p < 25 ? 1 : 2); }
__device__ __forceinline__ int cid_of(int mw, int n) {
  int td = n / 49, rr = n - td * 49, th = rr / 7, tw = rr - th * 7;
  int d = (mw >> 4) * 7 + td, h = ((mw >> 2) & 3) * 7 + th, w = (mw & 3) * 7 + tw;
  return zone3(d) * 9 + zone3(h) * 3 + zone3(w);
}

// ---------------- dtype detector ----------------
__global__ __launch_bounds__(64) void detect_kernel(const u16* __restrict__ x, int* __restrict__ flag) {
  int lane = threadIdx.x;
  int bad = 0;
  #pragma unroll
  for (int q = 0; q < 8; q++) {
    u16 b = x[(lane * 8 + q) * 2];
    int e = (b >> 7) & 0xff;
    if (e >= 0x90) bad = 1;
  }
  unsigned long long m = __ballot(bad);
  if (lane == 0) *flag = (m != 0ull) ? 1 : 0;
}

// ---------------- weight conversion -> bf16 [n][k] concat ----------------
__global__ __launch_bounds__(256) void wconv_kernel(
    const void* __restrict__ w0, const void* __restrict__ w1,
    const void* __restrict__ w2, const void* __restrict__ w3,
    u16* __restrict__ out, const int* __restrict__ dflag) {
  int f32 = __builtin_amdgcn_readfirstlane(dflag[0]);
  int g = blockIdx.x * 256 + threadIdx.x;
  if (g >= 110592) return;
  float v;
  if (g < 27648)      v = ldf(w0, f32, g);
  else if (g < 36864) v = ldf(w1, f32, g - 27648);
  else if (g < 73728) v = ldf(w2, f32, g - 36864);
  else                v = ldf(w3, f32, g - 73728);
  out[g] = f2bf(v);
}

// ---------------- LN1 + shift + window partition gather ----------------
__global__ __launch_bounds__(256) void ln_gather_kernel(
    const void* __restrict__ x, const void* __restrict__ g, const void* __restrict__ b,
    u16* __restrict__ outw, const int* __restrict__ dflag) {
  int f32 = __builtin_amdgcn_readfirstlane(dflag[0]);
  int t = blockIdx.x * 4 + (threadIdx.x >> 6);
  int lane = threadIdx.x & 63;
  size_t base = spatial_base(t);
  int c = lane * 2;
  float vx = 0.f, vy = 0.f;
  if (c < 96) { float2 p = ld2(x, f32, base + c); vx = p.x; vy = p.y; }
  float s = vx + vy, ss = vx * vx + vy * vy;
  #pragma unroll
  for (int o = 1; o < 64; o <<= 1) { s += __shfl_xor(s, o); ss += __shfl_xor(ss, o); }
  float mean = s * (1.f / 96.f);
  float var = ss * (1.f / 96.f) - mean * mean;
  float rstd = rsqrtf(var + 1e-5f);
  if (c < 96) {
    float2 gp = ld2(g, f32, c), bp = ld2(b, f32, c);
    float y0 = (vx - mean) * rstd * gp.x + bp.x;
    float y1 = (vy - mean) * rstd * gp.y + bp.y;
    *(u32*)(outw + (size_t)t * 96 + c) = (u32)f2bf(y0) | ((u32)f2bf(y1) << 16);
  }
}

// ---------------- B3M: (bias + mask) * log2e, per window-class ----------------
// b3m[cls][head][row][col 352]; cls bit2=wd==3, bit1=wh==3, bit0=ww==3.
__global__ __launch_bounds__(256) void b3m_kernel(
    const void* __restrict__ bias_table, const int* __restrict__ rel,
    u16* __restrict__ b3m, const int* __restrict__ dflag) {
  int f32 = __builtin_amdgcn_readfirstlane(dflag[0]);
  int row = blockIdx.x;
  int by = blockIdx.y;            // cls*3 + head
  int cls = by / 3, head = by - cls * 3;
  int mw = ((cls & 4) ? 48 : 0) | ((cls & 2) ? 12 : 0) | ((cls & 1) ? 3 : 0);
  int cidq = cid_of(mw, row);
  for (int col = threadIdx.x; col < 352; col += 256) {
    float v = -MASKV;
    if (col < 343) {
      v = ldf(bias_table, f32, (size_t)rel[row * 343 + col] * 3 + head) * LOG2E;
      if (cid_of(mw, col) != cidq) v -= MASKV;
    }
    b3m[((size_t)by * 343 + row) * 352 + col] = f2bf(v);
  }
}

// ---------------- QKV MFMA GEMM -> planar [sel*3+head][tok][32] ----------------
// grid = (343, 3), block = 256. q-plane scaled by log2e/sqrt(32).
__global__ __launch_bounds__(256) void qkv_kernel(
    const u16* __restrict__ A, const u16* __restrict__ Wb, const void* __restrict__ bias,
    u16* __restrict__ outp, const int* __restrict__ dflag) {
  int f32 = __builtin_amdgcn_readfirstlane(dflag[0]);
  __shared__ alignas(16) u16 As[128 * 104];
  __shared__ alignas(16) u16 Ws[96 * 104];
  int tid = threadIdx.x;
  int m0 = blockIdx.x * 128, n0 = blockIdx.y * 96;
  int w = tid >> 6, lane = tid & 63, quad = lane >> 4, l16 = lane & 15;
  f32x4 acc[2][6];
  #pragma unroll
  for (int i = 0; i < 2; i++)
    #pragma unroll
    for (int j = 0; j < 6; j++) acc[i][j] = (f32x4){0.f, 0.f, 0.f, 0.f};
  for (int i = tid; i < 1536; i += 256) {
    int row = i / 12; int c = (i - row * 12) * 8;
    *(uint4*)&As[row * 104 + c] = *(const uint4*)(A + (size_t)(m0 + row) * 96 + c);
  }
  for (int i = tid; i < 1152; i += 256) {
    int row = i / 12; int c = (i - row * 12) * 8;
    *(uint4*)&Ws[row * 104 + c] = *(const uint4*)(Wb + (size_t)(n0 + row) * 96 + c);
  }
  __syncthreads();
  #pragma unroll
  for (int kc = 0; kc < 3; kc++) {
    s16x8 fa0 = *(const s16x8*)&As[(w * 32 + l16) * 104 + kc * 32 + quad * 8];
    s16x8 fa1 = *(const s16x8*)&As[(w * 32 + 16 + l16) * 104 + kc * 32 + quad * 8];
    #pragma unroll
    for (int j = 0; j < 6; j++) {
      s16x8 fb = *(const s16x8*)&Ws[(j * 16 + l16) * 104 + kc * 32 + quad * 8];
      acc[0][j] = __builtin_amdgcn_mfma_f32_16x16x32_bf16(fa0, fb, acc[0][j], 0, 0, 0);
      acc[1][j] = __builtin_amdgcn_mfma_f32_16x16x32_bf16(fa1, fb, acc[1][j], 0, 0, 0);
    }
  }
  #pragma unroll
  for (int i = 0; i < 2; i++) {
    #pragma unroll
    for (int r = 0; r < 4; r++) {
      int mm = m0 + w * 32 + i * 16 + quad * 4 + r;
      #pragma unroll
      for (int j = 0; j < 6; j++) {
        int nn = n0 + j * 16 + l16;
        float v = acc[i][j][r] + ldf(bias, f32, nn);
        int sel = nn / 96, hd = (nn - sel * 96) >> 5, cc = nn & 31;
        float scl = (sel == 0) ? 0.25504208f : 1.0f;   // log2e / sqrt(32)
        outp[((size_t)(sel * 3 + hd) * T_TOK + mm) * 32 + cc] = f2bf(v * scl);
      }
    }
  }
}

// ---------------- MFMA flash attention v3 ----------------
// grid = (3, 384), block = 512 (8 waves, 16 q-rows each; 128 q-rows/block).
__device__ __forceinline__ int vsw(int ch) { return ((ch >> 1) ^ (ch >> 3)) & 3; }

__global__ __launch_bounds__(512) void attn_mfma_kernel(
    const u16* __restrict__ qkv, const u16* __restrict__ b3m,
    u16* __restrict__ attnb) {
  __shared__ alignas(16) u16 Ks[352 * 32];   // idx = tok*32 + 8*((ch>>3)^(tok&3)) + (ch&7)
  __shared__ alignas(16) u16 Vt[32 * 352];   // idx = ch*352 + 8*((tok>>3)^vsw(ch)) + (tok&7)
  __shared__ alignas(16) u16 Ps[8][512];     // idx = q*32 + 8*((k32>>3)^swl(q)) + (k32&7)

  int tid = threadIdx.x;
  int wh = blockIdx.y;
  int head = wh % 3;
  int win = wh / 3;
  int mw = win & 63;
  int cls = (((mw >> 4) == 3) ? 4 : 0) | ((((mw >> 2) & 3) == 3) ? 2 : 0) | (((mw & 3) == 3) ? 1 : 0);
  int m0 = blockIdx.x * 128;
  size_t wbase = (size_t)win * NTOK;

  const u16* qplane = qkv + ((size_t)head * T_TOK + wbase) * 32;
  const u16* kplane = qkv + ((size_t)(3 + head) * T_TOK + wbase) * 32;
  const u16* vplane = qkv + ((size_t)(6 + head) * T_TOK + wbase) * 32;

  // stage K rows 0..351 (343+ zero)
  for (int i = tid; i < 1408; i += 512) {
    int tok = i >> 2, cb = i & 3;
    uint4 kv = make_uint4(0, 0, 0, 0);
    if (tok < 343) kv = *(const uint4*)(kplane + (size_t)tok * 32 + cb * 8);
    *(uint4*)&Ks[tok * 32 + 8 * (cb ^ (tok & 3))] = kv;
  }
  // stage V^T (token-pair u32 writes, conflict-free swizzle)
  for (int i = tid; i < 688; i += 512) {
    int p = i >> 2, cb = (i & 3) * 8;
    int t0 = 2 * p;
    uint4 v0 = *(const uint4*)(vplane + (size_t)t0 * 32 + cb);
    uint4 v1 = make_uint4(0, 0, 0, 0);
    if (t0 + 1 < 343) v1 = *(const uint4*)(vplane + (size_t)(t0 + 1) * 32 + cb);
    u32 a0[4] = {v0.x, v0.y, v0.z, v0.w};
    u32 a1[4] = {v1.x, v1.y, v1.z, v1.w};
    int blk = t0 >> 3, tin = (t0 & 7) >> 1;
    #pragma unroll
    for (int q = 0; q < 4; q++) {
      int ch0 = cb + 2 * q;
      u32 w0v = (a0[q] & 0xffffu) | ((a1[q] & 0xffffu) << 16);
      u32 w1v = (a0[q] >> 16) | (a1[q] & 0xffff0000u);
      ((u32*)Vt)[ch0 * 176 + 4 * (blk ^ vsw(ch0)) + tin] = w0v;
      ((u32*)Vt)[(ch0 + 1) * 176 + 4 * (blk ^ vsw(ch0 + 1)) + tin] = w1v;
    }
  }
  // zero V^T pad toks 344..351 (blk 43)
  if (tid < 256) {
    int ch = tid >> 3, j = tid & 7;
    Vt[ch * 352 + 8 * (43 ^ vsw(ch)) + j] = 0;
  }
  __syncthreads();

  int w = tid >> 6, lane = tid & 63, quad = lane >> 4, l16 = lane & 15;
  int qbase = m0 + w * 16;
  int qrow_l = qbase + l16;
  int qc = qrow_l < NTOK ? qrow_l : NTOK - 1;
  s16x8 fq = *(const s16x8*)(qplane + (size_t)qc * 32 + quad * 8);
  const u16* bmrow = b3m + ((size_t)(cls * 3 + head) * 343 + qc) * 352;
  int swl = (l16 ^ (l16 >> 2)) & 3;
  int vsw0 = vsw(l16), vsw1 = vsw(16 + l16);

  float lsum = 0.f;
  f32x4 o0 = {0.f, 0.f, 0.f, 0.f}, o1 = {0.f, 0.f, 0.f, 0.f};
  const f32x4 zz = {0.f, 0.f, 0.f, 0.f};

  for (int t32 = 0; t32 < 11; t32++) {
    #pragma unroll
    for (int h = 0; h < 2; h++) {
      int kb = t32 * 32 + h * 16;
      int ktok = kb + l16;
      s16x8 fk = *(const s16x8*)&Ks[ktok * 32 + 8 * (quad ^ (ktok & 3))];
      f32x4 st = __builtin_amdgcn_mfma_f32_16x16x32_bf16(fk, fq, zz, 0, 0, 0);
      uint2 bm = *(const uint2*)(bmrow + kb + quad * 4);
      float p0 = exp2f(st[0] + bf2f(bm.x & 0xffff));
      float p1 = exp2f(st[1] + bf2f(bm.x >> 16));
      float p2 = exp2f(st[2] + bf2f(bm.y & 0xffff));
      float p3 = exp2f(st[3] + bf2f(bm.y >> 16));
      lsum += (p0 + p1) + (p2 + p3);
      u32 pa = (__float_as_uint(p0) >> 16) | (__float_as_uint(p1) & 0xffff0000u);
      u32 pb = (__float_as_uint(p2) >> 16) | (__float_as_uint(p3) & 0xffff0000u);
      int blkp = h * 2 + (quad >> 1);
      *(uint2*)&Ps[w][l16 * 32 + 8 * (blkp ^ swl) + (quad & 1) * 4] = make_uint2(pa, pb);
    }
    // per-wave private Ps: wave-internal LDS ordering, no barrier
    s16x8 fp  = *(const s16x8*)&Ps[w][l16 * 32 + 8 * (quad ^ swl)];
    s16x8 fv0 = *(const s16x8*)&Vt[l16 * 352 + 8 * ((t32 * 4 + quad) ^ vsw0)];
    s16x8 fv1 = *(const s16x8*)&Vt[(16 + l16) * 352 + 8 * ((t32 * 4 + quad) ^ vsw1)];
    o0 = __builtin_amdgcn_mfma_f32_16x16x32_bf16(fp, fv0, o0, 0, 0, 0);
    o1 = __builtin_amdgcn_mfma_f32_16x16x32_bf16(fp, fv1, o1, 0, 0, 0);
  }

  lsum += __shfl_xor(lsum, 16);
  lsum += __shfl_xor(lsum, 32);
  #pragma unroll
  for (int r = 0; r < 4; r++) {
    int qrow = qbase + quad * 4 + r;
    float ls = __shfl(lsum, quad * 4 + r);
    if (qrow < NTOK) {
      float rs = 1.0f / ls;
      size_t ob = (wbase + qrow) * 96 + head * 32;
      attnb[ob + l16] = f2bf(o0[r] * rs);
      attnb[ob + 16 + l16] = f2bf(o1[r] * rs);
    }
  }
}

// ---------------- mega-fused MLP: proj+res+LN2+FC1+GELU+FC2+res+scatter ----------------
// grid = 686 (64 rows/block), block = 256 (4 waves x 16 rows).
// Round-0 proven structure; only change: erff-GELU -> tanh-GELU (hw exp2 + v_rcp).
// tanh-GELU deviates from exact erf-GELU by <=3e-4, an order below the bf16
// quantization (ulp ~0.008) already applied to As2.
__global__ __launch_bounds__(256) void mlp_fused_kernel(
    const u16* __restrict__ attnb, const u16* __restrict__ wcat,
    const void* __restrict__ x, const void* __restrict__ b_proj,
    const void* __restrict__ g2, const void* __restrict__ b2,
    const void* __restrict__ b_fc1, const void* __restrict__ b_fc2,
    void* __restrict__ outp, const int* __restrict__ dflag) {
  int f32 = __builtin_amdgcn_readfirstlane(dflag[0]);
  __shared__ alignas(16) u16 As[64 * 104];
  __shared__ alignas(16) u16 As2[64 * 104];
  __shared__ alignas(16) u16 Ws[96 * 104];
  const u16* w_projb = wcat + 27648;
  const u16* w_fc1b  = wcat + 36864;
  const u16* w_fc2b  = wcat + 73728;
  int tid = threadIdx.x, m0 = blockIdx.x * 64;
  int w = tid >> 6, lane = tid & 63, quad = lane >> 4, l16 = lane & 15;

  // stage attn rows + w_proj
  for (int i = tid; i < 768; i += 256) {
    int row = i / 12, c = (i - row * 12) * 8;
    *(uint4*)&As[row * 104 + c] = *(const uint4*)(attnb + (size_t)(m0 + row) * 96 + c);
  }
  for (int i = tid; i < 1152; i += 256) {
    int row = i / 12, c = (i - row * 12) * 8;
    *(uint4*)&Ws[row * 104 + c] = *(const uint4*)(w_projb + row * 96 + c);
  }
  __syncthreads();
  f32x4 accp[6];
  #pragma unroll
  for (int j = 0; j < 6; j++) accp[j] = (f32x4){0.f, 0.f, 0.f, 0.f};
  #pragma unroll
  for (int kc = 0; kc < 3; kc++) {
    s16x8 fa = *(const s16x8*)&As[(w * 16 + l16) * 104 + kc * 32 + quad * 8];
    #pragma unroll
    for (int j = 0; j < 6; j++) {
      s16x8 fb = *(const s16x8*)&Ws[(j * 16 + l16) * 104 + kc * 32 + quad * 8];
      accp[j] = __builtin_amdgcn_mfma_f32_16x16x32_bf16(fa, fb, accp[j], 0, 0, 0);
    }
  }
  __syncthreads();   // all waves done reading As/Ws before overwrite

  // epilogue 1: + b_proj + x -> rv ; LN2 -> As (own-wave slab)
  float bp[6], gv[6], b2v[6];
  #pragma unroll
  for (int j = 0; j < 6; j++) {
    int nn = j * 16 + l16;
    bp[j] = ldf(b_proj, f32, nn); gv[j] = ldf(g2, f32, nn); b2v[j] = ldf(b2, f32, nn);
  }
  float rv[4][6];
  size_t sb[4];
  #pragma unroll
  for (int r = 0; r < 4; r++) {
    int mm = m0 + w * 16 + quad * 4 + r;
    sb[r] = spatial_base(mm);
    float s = 0.f, ss = 0.f;
    #pragma unroll
    for (int j = 0; j < 6; j++) {
      float v = accp[j][r] + bp[j] + ldf(x, f32, sb[r] + j * 16 + l16);
      rv[r][j] = v; s += v; ss += v * v;
    }
    #pragma unroll
    for (int o = 1; o < 16; o <<= 1) { s += __shfl_xor(s, o); ss += __shfl_xor(ss, o); }
    float mean = s * (1.f / 96.f);
    float var = ss * (1.f / 96.f) - mean * mean;
    float rstd = rsqrtf(var + 1e-5f);
    #pragma unroll
    for (int j = 0; j < 6; j++)
      As[(w * 16 + quad * 4 + r) * 104 + j * 16 + l16] = f2bf((rv[r][j] - mean) * rstd * gv[j] + b2v[j]);
  }

  f32x4 acc2[6];
  #pragma unroll
  for (int j = 0; j < 6; j++) acc2[j] = (f32x4){0.f, 0.f, 0.f, 0.f};
  for (int c = 0; c < 4; c++) {
    __syncthreads();
    for (int i = tid; i < 1152; i += 256) {
      int row = i / 12, cc = (i - row * 12) * 8;
      *(uint4*)&Ws[row * 104 + cc] = *(const uint4*)(w_fc1b + (size_t)(96 * c + row) * 96 + cc);
    }
    __syncthreads();
    f32x4 a1[6];
    #pragma unroll
    for (int j = 0; j < 6; j++) a1[j] = (f32x4){0.f, 0.f, 0.f, 0.f};
    #pragma unroll
    for (int kc = 0; kc < 3; kc++) {
      s16x8 fa = *(const s16x8*)&As[(w * 16 + l16) * 104 + kc * 32 + quad * 8];
      #pragma unroll
      for (int j = 0; j < 6; j++) {
        s16x8 fb = *(const s16x8*)&Ws[(j * 16 + l16) * 104 + kc * 32 + quad * 8];
        a1[j] = __builtin_amdgcn_mfma_f32_16x16x32_bf16(fa, fb, a1[j], 0, 0, 0);
      }
    }
    #pragma unroll
    for (int j = 0; j < 6; j++) {
      float bf1 = ldf(b_fc1, f32, 96 * c + j * 16 + l16);
      #pragma unroll
      for (int r = 0; r < 4; r++) {
        float v = a1[j][r] + bf1;
        // tanh-GELU: v - v * rcp(exp2(2*log2e*0.7978845608*(v + 0.044715 v^3)) + 1)
        float vv = v * v;
        float p = fmaf(0.044715f, vv, 1.0f);
        float z = 2.3022078f * v * p;
        float e = exp2f(z);
        float rcp = __builtin_amdgcn_rcpf(e + 1.0f);
        v = v - v * rcp;
        As2[(w * 16 + quad * 4 + r) * 104 + j * 16 + l16] = f2bf(v);
      }
    }
    __syncthreads();
    for (int i = tid; i < 1152; i += 256) {
      int row = i / 12, cc = (i - row * 12) * 8;
      *(uint4*)&Ws[row * 104 + cc] = *(const uint4*)(w_fc2b + (size_t)row * 384 + 96 * c + cc);
    }
    __syncthreads();
    #pragma unroll
    for (int kc = 0; kc < 3; kc++) {
      s16x8 fa2 = *(const s16x8*)&As2[(w * 16 + l16) * 104 + kc * 32 + quad * 8];
      #pragma unroll
      for (int j = 0; j < 6; j++) {
        s16x8 fb = *(const s16x8*)&Ws[(j * 16 + l16) * 104 + kc * 32 + quad * 8];
        acc2[j] = __builtin_amdgcn_mfma_f32_16x16x32_bf16(fa2, fb, acc2[j], 0, 0, 0);
      }
    }
  }
  // final: + b_fc2 + rv -> out at spatial location
  float bf2v[6];
  #pragma unroll
  for (int j = 0; j < 6; j++) bf2v[j] = ldf(b_fc2, f32, j * 16 + l16);
  #pragma unroll
  for (int r = 0; r < 4; r++) {
    #pragma unroll
    for (int j = 0; j < 6; j++) {
      float v = acc2[j][r] + bf2v[j] + rv[r][j];
      if (f32) ((float*)outp)[sb[r] + j * 16 + l16] = v;
      else     ((u16*)outp)[sb[r] + j * 16 + l16] = f2bf(v);
    }
  }
}

extern "C" void kernel_launch(void* const* d_in, const int* in_sizes, int n_in,
                              void* d_out, int out_size, void* d_ws, size_t ws_size,
                              hipStream_t stream) {
  (void)in_sizes; (void)n_in; (void)out_size; (void)ws_size;
  const void* x       = d_in[0];
  const void* g1      = d_in[2];
  const void* b1      = d_in[3];
  const void* w_qkv   = d_in[4];
  const void* b_qkv   = d_in[5];
  const void* bias_tb = d_in[6];
  const void* w_proj  = d_in[7];
  const void* b_proj  = d_in[8];
  const void* g2      = d_in[9];
  const void* b2      = d_in[10];
  const void* w_fc1   = d_in[11];
  const void* b_fc1   = d_in[12];
  const void* w_fc2   = d_in[13];
  const void* b_fc2   = d_in[14];
  const int* rel_idx  = (const int*)d_in[15];

  // workspace (~48.2 MB): dflag | winb 8.43M | qkvb 25.3M | attnb 8.43M | b3m 5.80M | wcat 0.22M
  char* ws = (char*)d_ws;
  int*  dflag = (int*)ws;
  u16*  winb  = (u16*)(ws + 256);
  u16*  qkvb  = (u16*)(ws + 8429824);
  u16*  attnb = (u16*)(ws + 33718528);
  u16*  b3mb  = (u16*)(ws + 42148096);
  u16*  wcat  = (u16*)(ws + 47943424);
  u16*  w_qkvb = wcat;

  detect_kernel<<<1, 64, 0, stream>>>((const u16*)x, dflag);
  wconv_kernel<<<432, 256, 0, stream>>>(w_qkv, w_proj, w_fc1, w_fc2, wcat, dflag);
  b3m_kernel<<<dim3(343, 24), 256, 0, stream>>>(bias_tb, rel_idx, b3mb, dflag);
  // 1. LN1 + shift + window partition
  ln_gather_kernel<<<T_TOK / 4, 256, 0, stream>>>(x, g1, b1, winb, dflag);
  // 2. QKV GEMM -> planar qkv (q pre-scaled by log2e/sqrt(32))
  qkv_kernel<<<dim3(343, 3), 256, 0, stream>>>(winb, w_qkvb, b_qkv, qkvb, dflag);
  // 3. flash attention -> attnb
  attn_mfma_kernel<<<dim3(3, 384), 512, 0, stream>>>(qkvb, b3mb, attnb);
  // 4. proj + residual + LN2 + FC1 + GELU + FC2 + residual + scatter -> d_out
  mlp_fused_kernel<<<686, 256, 0, stream>>>(attnb, wcat, x, b_proj, g2, b2,
                                            b_fc1, b_fc2, d_out, dflag);
}

// Round 8
// 212.973 us; speedup vs baseline: 1.3214x; 1.0582x over previous
//
#include <hip/hip_runtime.h>
#include <hip/hip_bf16.h>
#include <math.h>

typedef unsigned short u16;
typedef unsigned int u32;
typedef unsigned char u8;

#define T_TOK 43904   // 128 windows * 343 tokens
#define NTOK 343
#define LOG2E 1.4426950408889634f
#define MASKV 144.26950408889634f   // 100 * log2(e)

typedef __attribute__((ext_vector_type(4))) float f32x4;
typedef __attribute__((ext_vector_type(8))) short s16x8;

__device__ __forceinline__ float bf2f(u32 v) { return __uint_as_float(v << 16); }
__device__ __forceinline__ u16 f2bf(float f) {
  u32 u = __float_as_uint(f);
  return (u16)((u + 0x7fffu + ((u >> 16) & 1u)) >> 16);
}

// ---- dual-dtype input loaders: f32!=0 -> data is fp32, else packed bf16 ----
__device__ __forceinline__ float ldf(const void* p, int f32, size_t i) {
  return f32 ? ((const float*)p)[i] : bf2f(((const u16*)p)[i]);
}
__device__ __forceinline__ float2 ld2(const void* p, int f32, size_t i) {  // i even
  if (f32) return *(const float2*)((const float*)p + i);
  u32 pk = *(const u32*)((const u16*)p + i);
  return make_float2(bf2f(pk & 0xffff), bf2f(pk >> 16));
}

// token index t (window-major) -> element offset of the (b,d,h,w) voxel in x/out
__device__ __forceinline__ size_t spatial_base(int t) {
  int win = t / 343, n = t - win * 343;
  int bb = win >> 6, wrem = win & 63;
  int wd = wrem >> 4, wh = (wrem >> 2) & 3, ww = wrem & 3;
  int td = n / 49; int r = n - td * 49; int th = r / 7; int tw = r - th * 7;
  int d0 = wd * 7 + td + 3; if (d0 >= 28) d0 -= 28;
  int h0 = wh * 7 + th + 3; if (h0 >= 28) h0 -= 28;
  int w0 = ww * 7 + tw + 3; if (w0 >= 28) w0 -= 28;
  return (size_t)(((bb * 28 + d0) * 28 + h0) * 28 + w0) * 96;
}

// shifted-window mask region id (exact reproduction of MONAI compute_mask)
__device__ __forceinline__ int zone3(int p) { return p < 21 ? 0 : (p < 25 ? 1 : 2); }
__device__ __forceinline__ int cid_of(int mw, int n) {
  int td = n / 49, rr = n - td * 49, th = rr / 7, tw = rr - th * 7;
  int d = (mw >> 4) * 7 + td, h = ((mw >> 2) & 3) * 7 + th, w = (mw & 3) * 7 + tw;
  return zone3(d) * 9 + zone3(h) * 3 + zone3(w);
}

// ---------------- dtype detector ----------------
__global__ __launch_bounds__(64) void detect_kernel(const u16* __restrict__ x, int* __restrict__ flag) {
  int lane = threadIdx.x;
  int bad = 0;
  #pragma unroll
  for (int q = 0; q < 8; q++) {
    u16 b = x[(lane * 8 + q) * 2];
    int e = (b >> 7) & 0xff;
    if (e >= 0x90) bad = 1;
  }
  unsigned long long m = __ballot(bad);
  if (lane == 0) *flag = (m != 0ull) ? 1 : 0;
}

// ---------------- weight conversion -> bf16 [n][k] concat ----------------
__global__ __launch_bounds__(256) void wconv_kernel(
    const void* __restrict__ w0, const void* __restrict__ w1,
    const void* __restrict__ w2, const void* __restrict__ w3,
    u16* __restrict__ out, const int* __restrict__ dflag) {
  int f32 = __builtin_amdgcn_readfirstlane(dflag[0]);
  int g = blockIdx.x * 256 + threadIdx.x;
  if (g >= 110592) return;
  float v;
  if (g < 27648)      v = ldf(w0, f32, g);
  else if (g < 36864) v = ldf(w1, f32, g - 27648);
  else if (g < 73728) v = ldf(w2, f32, g - 36864);
  else                v = ldf(w3, f32, g - 73728);
  out[g] = f2bf(v);
}

// ---------------- LN1 + shift + window partition gather ----------------
__global__ __launch_bounds__(256) void ln_gather_kernel(
    const void* __restrict__ x, const void* __restrict__ g, const void* __restrict__ b,
    u16* __restrict__ outw, const int* __restrict__ dflag) {
  int f32 = __builtin_amdgcn_readfirstlane(dflag[0]);
  int t = blockIdx.x * 4 + (threadIdx.x >> 6);
  int lane = threadIdx.x & 63;
  size_t base = spatial_base(t);
  int c = lane * 2;
  float vx = 0.f, vy = 0.f;
  if (c < 96) { float2 p = ld2(x, f32, base + c); vx = p.x; vy = p.y; }
  float s = vx + vy, ss = vx * vx + vy * vy;
  #pragma unroll
  for (int o = 1; o < 64; o <<= 1) { s += __shfl_xor(s, o); ss += __shfl_xor(ss, o); }
  float mean = s * (1.f / 96.f);
  float var = ss * (1.f / 96.f) - mean * mean;
  float rstd = rsqrtf(var + 1e-5f);
  if (c < 96) {
    float2 gp = ld2(g, f32, c), bp = ld2(b, f32, c);
    float y0 = (vx - mean) * rstd * gp.x + bp.x;
    float y1 = (vy - mean) * rstd * gp.y + bp.y;
    *(u32*)(outw + (size_t)t * 96 + c) = (u32)f2bf(y0) | ((u32)f2bf(y1) << 16);
  }
}

// ---------------- B3M: (bias + mask) * log2e, per window-class ----------------
// b3m[cls][head][row][col 352]; cls bit2=wd==3, bit1=wh==3, bit0=ww==3.
__global__ __launch_bounds__(256) void b3m_kernel(
    const void* __restrict__ bias_table, const int* __restrict__ rel,
    u16* __restrict__ b3m, const int* __restrict__ dflag) {
  int f32 = __builtin_amdgcn_readfirstlane(dflag[0]);
  int row = blockIdx.x;
  int by = blockIdx.y;            // cls*3 + head
  int cls = by / 3, head = by - cls * 3;
  int mw = ((cls & 4) ? 48 : 0) | ((cls & 2) ? 12 : 0) | ((cls & 1) ? 3 : 0);
  int cidq = cid_of(mw, row);
  for (int col = threadIdx.x; col < 352; col += 256) {
    float v = -MASKV;
    if (col < 343) {
      v = ldf(bias_table, f32, (size_t)rel[row * 343 + col] * 3 + head) * LOG2E;
      if (cid_of(mw, col) != cidq) v -= MASKV;
    }
    b3m[((size_t)by * 343 + row) * 352 + col] = f2bf(v);
  }
}

// ---------------- QKV MFMA GEMM -> planar [sel*3+head][tok][32] ----------------
// grid = (343, 3), block = 256. q-plane scaled by log2e/sqrt(32).
// Epilogue: bias/scale/output-base hoisted per-j (bias is not restrict-qualified,
// so un-hoisted the compiler re-loads it and re-derives sel/hd/cc 8x per j).
__global__ __launch_bounds__(256) void qkv_kernel(
    const u16* __restrict__ A, const u16* __restrict__ Wb, const void* __restrict__ bias,
    u16* __restrict__ outp, const int* __restrict__ dflag) {
  int f32 = __builtin_amdgcn_readfirstlane(dflag[0]);
  __shared__ alignas(16) u16 As[128 * 104];
  __shared__ alignas(16) u16 Ws[96 * 104];
  int tid = threadIdx.x;
  int m0 = blockIdx.x * 128, n0 = blockIdx.y * 96;
  int w = tid >> 6, lane = tid & 63, quad = lane >> 4, l16 = lane & 15;
  f32x4 acc[2][6];
  #pragma unroll
  for (int i = 0; i < 2; i++)
    #pragma unroll
    for (int j = 0; j < 6; j++) acc[i][j] = (f32x4){0.f, 0.f, 0.f, 0.f};
  for (int i = tid; i < 1536; i += 256) {
    int row = i / 12; int c = (i - row * 12) * 8;
    *(uint4*)&As[row * 104 + c] = *(const uint4*)(A + (size_t)(m0 + row) * 96 + c);
  }
  for (int i = tid; i < 1152; i += 256) {
    int row = i / 12; int c = (i - row * 12) * 8;
    *(uint4*)&Ws[row * 104 + c] = *(const uint4*)(Wb + (size_t)(n0 + row) * 96 + c);
  }
  __syncthreads();
  #pragma unroll
  for (int kc = 0; kc < 3; kc++) {
    s16x8 fa0 = *(const s16x8*)&As[(w * 32 + l16) * 104 + kc * 32 + quad * 8];
    s16x8 fa1 = *(const s16x8*)&As[(w * 32 + 16 + l16) * 104 + kc * 32 + quad * 8];
    #pragma unroll
    for (int j = 0; j < 6; j++) {
      s16x8 fb = *(const s16x8*)&Ws[(j * 16 + l16) * 104 + kc * 32 + quad * 8];
      acc[0][j] = __builtin_amdgcn_mfma_f32_16x16x32_bf16(fa0, fb, acc[0][j], 0, 0, 0);
      acc[1][j] = __builtin_amdgcn_mfma_f32_16x16x32_bf16(fa1, fb, acc[1][j], 0, 0, 0);
    }
  }
  // hoisted per-j epilogue constants
  float bv[6], sclv[6];
  size_t obase[6];
  #pragma unroll
  for (int j = 0; j < 6; j++) {
    int nn = n0 + j * 16 + l16;
    bv[j] = ldf(bias, f32, nn);
    int sel = nn / 96, hd = (nn - sel * 96) >> 5, cc = nn & 31;
    sclv[j] = (sel == 0) ? 0.25504208f : 1.0f;   // log2e / sqrt(32)
    obase[j] = (size_t)(sel * 3 + hd) * T_TOK * 32 + cc;
  }
  #pragma unroll
  for (int i = 0; i < 2; i++) {
    #pragma unroll
    for (int r = 0; r < 4; r++) {
      int mm = m0 + w * 32 + i * 16 + quad * 4 + r;
      #pragma unroll
      for (int j = 0; j < 6; j++) {
        float v = (acc[i][j][r] + bv[j]) * sclv[j];
        outp[obase[j] + (size_t)mm * 32] = f2bf(v);
      }
    }
  }
}

// ---------------- MFMA flash attention v3 ----------------
// grid = (3, 384), block = 512 (8 waves, 16 q-rows each; 128 q-rows/block).
__device__ __forceinline__ int vsw(int ch) { return ((ch >> 1) ^ (ch >> 3)) & 3; }

__global__ __launch_bounds__(512) void attn_mfma_kernel(
    const u16* __restrict__ qkv, const u16* __restrict__ b3m,
    u16* __restrict__ attnb) {
  __shared__ alignas(16) u16 Ks[352 * 32];   // idx = tok*32 + 8*((ch>>3)^(tok&3)) + (ch&7)
  __shared__ alignas(16) u16 Vt[32 * 352];   // idx = ch*352 + 8*((tok>>3)^vsw(ch)) + (tok&7)
  __shared__ alignas(16) u16 Ps[8][512];     // idx = q*32 + 8*((k32>>3)^swl(q)) + (k32&7)

  int tid = threadIdx.x;
  int wh = blockIdx.y;
  int head = wh % 3;
  int win = wh / 3;
  int mw = win & 63;
  int cls = (((mw >> 4) == 3) ? 4 : 0) | ((((mw >> 2) & 3) == 3) ? 2 : 0) | (((mw & 3) == 3) ? 1 : 0);
  int m0 = blockIdx.x * 128;
  size_t wbase = (size_t)win * NTOK;

  const u16* qplane = qkv + ((size_t)head * T_TOK + wbase) * 32;
  const u16* kplane = qkv + ((size_t)(3 + head) * T_TOK + wbase) * 32;
  const u16* vplane = qkv + ((size_t)(6 + head) * T_TOK + wbase) * 32;

  // stage K rows 0..351 (343+ zero)
  for (int i = tid; i < 1408; i += 512) {
    int tok = i >> 2, cb = i & 3;
    uint4 kv = make_uint4(0, 0, 0, 0);
    if (tok < 343) kv = *(const uint4*)(kplane + (size_t)tok * 32 + cb * 8);
    *(uint4*)&Ks[tok * 32 + 8 * (cb ^ (tok & 3))] = kv;
  }
  // stage V^T (token-pair u32 writes, conflict-free swizzle)
  for (int i = tid; i < 688; i += 512) {
    int p = i >> 2, cb = (i & 3) * 8;
    int t0 = 2 * p;
    uint4 v0 = *(const uint4*)(vplane + (size_t)t0 * 32 + cb);
    uint4 v1 = make_uint4(0, 0, 0, 0);
    if (t0 + 1 < 343) v1 = *(const uint4*)(vplane + (size_t)(t0 + 1) * 32 + cb);
    u32 a0[4] = {v0.x, v0.y, v0.z, v0.w};
    u32 a1[4] = {v1.x, v1.y, v1.z, v1.w};
    int blk = t0 >> 3, tin = (t0 & 7) >> 1;
    #pragma unroll
    for (int q = 0; q < 4; q++) {
      int ch0 = cb + 2 * q;
      u32 w0v = (a0[q] & 0xffffu) | ((a1[q] & 0xffffu) << 16);
      u32 w1v = (a0[q] >> 16) | (a1[q] & 0xffff0000u);
      ((u32*)Vt)[ch0 * 176 + 4 * (blk ^ vsw(ch0)) + tin] = w0v;
      ((u32*)Vt)[(ch0 + 1) * 176 + 4 * (blk ^ vsw(ch0 + 1)) + tin] = w1v;
    }
  }
  // zero V^T pad toks 344..351 (blk 43)
  if (tid < 256) {
    int ch = tid >> 3, j = tid & 7;
    Vt[ch * 352 + 8 * (43 ^ vsw(ch)) + j] = 0;
  }
  __syncthreads();

  int w = tid >> 6, lane = tid & 63, quad = lane >> 4, l16 = lane & 15;
  int qbase = m0 + w * 16;
  int qrow_l = qbase + l16;
  int qc = qrow_l < NTOK ? qrow_l : NTOK - 1;
  s16x8 fq = *(const s16x8*)(qplane + (size_t)qc * 32 + quad * 8);
  const u16* bmrow = b3m + ((size_t)(cls * 3 + head) * 343 + qc) * 352;
  int swl = (l16 ^ (l16 >> 2)) & 3;
  int vsw0 = vsw(l16), vsw1 = vsw(16 + l16);

  float lsum = 0.f;
  f32x4 o0 = {0.f, 0.f, 0.f, 0.f}, o1 = {0.f, 0.f, 0.f, 0.f};
  const f32x4 zz = {0.f, 0.f, 0.f, 0.f};

  for (int t32 = 0; t32 < 11; t32++) {
    #pragma unroll
    for (int h = 0; h < 2; h++) {
      int kb = t32 * 32 + h * 16;
      int ktok = kb + l16;
      s16x8 fk = *(const s16x8*)&Ks[ktok * 32 + 8 * (quad ^ (ktok & 3))];
      f32x4 st = __builtin_amdgcn_mfma_f32_16x16x32_bf16(fk, fq, zz, 0, 0, 0);
      uint2 bm = *(const uint2*)(bmrow + kb + quad * 4);
      float p0 = exp2f(st[0] + bf2f(bm.x & 0xffff));
      float p1 = exp2f(st[1] + bf2f(bm.x >> 16));
      float p2 = exp2f(st[2] + bf2f(bm.y & 0xffff));
      float p3 = exp2f(st[3] + bf2f(bm.y >> 16));
      lsum += (p0 + p1) + (p2 + p3);
      u32 pa = (__float_as_uint(p0) >> 16) | (__float_as_uint(p1) & 0xffff0000u);
      u32 pb = (__float_as_uint(p2) >> 16) | (__float_as_uint(p3) & 0xffff0000u);
      int blkp = h * 2 + (quad >> 1);
      *(uint2*)&Ps[w][l16 * 32 + 8 * (blkp ^ swl) + (quad & 1) * 4] = make_uint2(pa, pb);
    }
    // per-wave private Ps: wave-internal LDS ordering, no barrier
    s16x8 fp  = *(const s16x8*)&Ps[w][l16 * 32 + 8 * (quad ^ swl)];
    s16x8 fv0 = *(const s16x8*)&Vt[l16 * 352 + 8 * ((t32 * 4 + quad) ^ vsw0)];
    s16x8 fv1 = *(const s16x8*)&Vt[(16 + l16) * 352 + 8 * ((t32 * 4 + quad) ^ vsw1)];
    o0 = __builtin_amdgcn_mfma_f32_16x16x32_bf16(fp, fv0, o0, 0, 0, 0);
    o1 = __builtin_amdgcn_mfma_f32_16x16x32_bf16(fp, fv1, o1, 0, 0, 0);
  }

  lsum += __shfl_xor(lsum, 16);
  lsum += __shfl_xor(lsum, 32);
  #pragma unroll
  for (int r = 0; r < 4; r++) {
    int qrow = qbase + quad * 4 + r;
    float ls = __shfl(lsum, quad * 4 + r);
    if (qrow < NTOK) {
      float rs = 1.0f / ls;
      size_t ob = (wbase + qrow) * 96 + head * 32;
      attnb[ob + l16] = f2bf(o0[r] * rs);
      attnb[ob + 16 + l16] = f2bf(o1[r] * rs);
    }
  }
}

// ---------------- mega-fused MLP: proj+res+LN2+FC1+GELU+FC2+res+scatter ----------------
// grid = 686 (64 rows/block), block = 256 (4 waves x 16 rows).
// Round-0 proven structure + tanh-GELU (hw exp2 + v_rcp; <=3e-4 vs erf-GELU,
// an order below the bf16 quantization already applied to As2).
__global__ __launch_bounds__(256) void mlp_fused_kernel(
    const u16* __restrict__ attnb, const u16* __restrict__ wcat,
    const void* __restrict__ x, const void* __restrict__ b_proj,
    const void* __restrict__ g2, const void* __restrict__ b2,
    const void* __restrict__ b_fc1, const void* __restrict__ b_fc2,
    void* __restrict__ outp, const int* __restrict__ dflag) {
  int f32 = __builtin_amdgcn_readfirstlane(dflag[0]);
  __shared__ alignas(16) u16 As[64 * 104];
  __shared__ alignas(16) u16 As2[64 * 104];
  __shared__ alignas(16) u16 Ws[96 * 104];
  const u16* w_projb = wcat + 27648;
  const u16* w_fc1b  = wcat + 36864;
  const u16* w_fc2b  = wcat + 73728;
  int tid = threadIdx.x, m0 = blockIdx.x * 64;
  int w = tid >> 6, lane = tid & 63, quad = lane >> 4, l16 = lane & 15;

  // stage attn rows + w_proj
  for (int i = tid; i < 768; i += 256) {
    int row = i / 12, c = (i - row * 12) * 8;
    *(uint4*)&As[row * 104 + c] = *(const uint4*)(attnb + (size_t)(m0 + row) * 96 + c);
  }
  for (int i = tid; i < 1152; i += 256) {
    int row = i / 12, c = (i - row * 12) * 8;
    *(uint4*)&Ws[row * 104 + c] = *(const uint4*)(w_projb + row * 96 + c);
  }
  __syncthreads();
  f32x4 accp[6];
  #pragma unroll
  for (int j = 0; j < 6; j++) accp[j] = (f32x4){0.f, 0.f, 0.f, 0.f};
  #pragma unroll
  for (int kc = 0; kc < 3; kc++) {
    s16x8 fa = *(const s16x8*)&As[(w * 16 + l16) * 104 + kc * 32 + quad * 8];
    #pragma unroll
    for (int j = 0; j < 6; j++) {
      s16x8 fb = *(const s16x8*)&Ws[(j * 16 + l16) * 104 + kc * 32 + quad * 8];
      accp[j] = __builtin_amdgcn_mfma_f32_16x16x32_bf16(fa, fb, accp[j], 0, 0, 0);
    }
  }
  __syncthreads();   // all waves done reading As/Ws before overwrite

  // epilogue 1: + b_proj + x -> rv ; LN2 -> As (own-wave slab)
  float bp[6], gv[6], b2v[6];
  #pragma unroll
  for (int j = 0; j < 6; j++) {
    int nn = j * 16 + l16;
    bp[j] = ldf(b_proj, f32, nn); gv[j] = ldf(g2, f32, nn); b2v[j] = ldf(b2, f32, nn);
  }
  float rv[4][6];
  size_t sb[4];
  #pragma unroll
  for (int r = 0; r < 4; r++) {
    int mm = m0 + w * 16 + quad * 4 + r;
    sb[r] = spatial_base(mm);
    float s = 0.f, ss = 0.f;
    #pragma unroll
    for (int j = 0; j < 6; j++) {
      float v = accp[j][r] + bp[j] + ldf(x, f32, sb[r] + j * 16 + l16);
      rv[r][j] = v; s += v; ss += v * v;
    }
    #pragma unroll
    for (int o = 1; o < 16; o <<= 1) { s += __shfl_xor(s, o); ss += __shfl_xor(ss, o); }
    float mean = s * (1.f / 96.f);
    float var = ss * (1.f / 96.f) - mean * mean;
    float rstd = rsqrtf(var + 1e-5f);
    #pragma unroll
    for (int j = 0; j < 6; j++)
      As[(w * 16 + quad * 4 + r) * 104 + j * 16 + l16] = f2bf((rv[r][j] - mean) * rstd * gv[j] + b2v[j]);
  }

  f32x4 acc2[6];
  #pragma unroll
  for (int j = 0; j < 6; j++) acc2[j] = (f32x4){0.f, 0.f, 0.f, 0.f};
  for (int c = 0; c < 4; c++) {
    __syncthreads();
    for (int i = tid; i < 1152; i += 256) {
      int row = i / 12, cc = (i - row * 12) * 8;
      *(uint4*)&Ws[row * 104 + cc] = *(const uint4*)(w_fc1b + (size_t)(96 * c + row) * 96 + cc);
    }
    __syncthreads();
    f32x4 a1[6];
    #pragma unroll
    for (int j = 0; j < 6; j++) a1[j] = (f32x4){0.f, 0.f, 0.f, 0.f};
    #pragma unroll
    for (int kc = 0; kc < 3; kc++) {
      s16x8 fa = *(const s16x8*)&As[(w * 16 + l16) * 104 + kc * 32 + quad * 8];
      #pragma unroll
      for (int j = 0; j < 6; j++) {
        s16x8 fb = *(const s16x8*)&Ws[(j * 16 + l16) * 104 + kc * 32 + quad * 8];
        a1[j] = __builtin_amdgcn_mfma_f32_16x16x32_bf16(fa, fb, a1[j], 0, 0, 0);
      }
    }
    #pragma unroll
    for (int j = 0; j < 6; j++) {
      float bf1 = ldf(b_fc1, f32, 96 * c + j * 16 + l16);
      #pragma unroll
      for (int r = 0; r < 4; r++) {
        float v = a1[j][r] + bf1;
        // tanh-GELU: v - v * rcp(exp2(2*log2e*0.7978845608*(v + 0.044715 v^3)) + 1)
        float vv = v * v;
        float p = fmaf(0.044715f, vv, 1.0f);
        float z = 2.3022078f * v * p;
        float e = exp2f(z);
        float rcp = __builtin_amdgcn_rcpf(e + 1.0f);
        v = v - v * rcp;
        As2[(w * 16 + quad * 4 + r) * 104 + j * 16 + l16] = f2bf(v);
      }
    }
    __syncthreads();
    for (int i = tid; i < 1152; i += 256) {
      int row = i / 12, cc = (i - row * 12) * 8;
      *(uint4*)&Ws[row * 104 + cc] = *(const uint4*)(w_fc2b + (size_t)row * 384 + 96 * c + cc);
    }
    __syncthreads();
    #pragma unroll
    for (int kc = 0; kc < 3; kc++) {
      s16x8 fa2 = *(const s16x8*)&As2[(w * 16 + l16) * 104 + kc * 32 + quad * 8];
      #pragma unroll
      for (int j = 0; j < 6; j++) {
        s16x8 fb = *(const s16x8*)&Ws[(j * 16 + l16) * 104 + kc * 32 + quad * 8];
        acc2[j] = __builtin_amdgcn_mfma_f32_16x16x32_bf16(fa2, fb, acc2[j], 0, 0, 0);
      }
    }
  }
  // final: + b_fc2 + rv -> out at spatial location
  float bf2v[6];
  #pragma unroll
  for (int j = 0; j < 6; j++) bf2v[j] = ldf(b_fc2, f32, j * 16 + l16);
  #pragma unroll
  for (int r = 0; r < 4; r++) {
    #pragma unroll
    for (int j = 0; j < 6; j++) {
      float v = acc2[j][r] + bf2v[j] + rv[r][j];
      if (f32) ((float*)outp)[sb[r] + j * 16 + l16] = v;
      else     ((u16*)outp)[sb[r] + j * 16 + l16] = f2bf(v);
    }
  }
}

extern "C" void kernel_launch(void* const* d_in, const int* in_sizes, int n_in,
                              void* d_out, int out_size, void* d_ws, size_t ws_size,
                              hipStream_t stream) {
  (void)in_sizes; (void)n_in; (void)out_size; (void)ws_size;
  const void* x       = d_in[0];
  const void* g1      = d_in[2];
  const void* b1      = d_in[3];
  const void* w_qkv   = d_in[4];
  const void* b_qkv   = d_in[5];
  const void* bias_tb = d_in[6];
  const void* w_proj  = d_in[7];
  const void* b_proj  = d_in[8];
  const void* g2      = d_in[9];
  const void* b2      = d_in[10];
  const void* w_fc1   = d_in[11];
  const void* b_fc1   = d_in[12];
  const void* w_fc2   = d_in[13];
  const void* b_fc2   = d_in[14];
  const int* rel_idx  = (const int*)d_in[15];

  // workspace (~48.2 MB): dflag | winb 8.43M | qkvb 25.3M | attnb 8.43M | b3m 5.80M | wcat 0.22M
  char* ws = (char*)d_ws;
  int*  dflag = (int*)ws;
  u16*  winb  = (u16*)(ws + 256);
  u16*  qkvb  = (u16*)(ws + 8429824);
  u16*  attnb = (u16*)(ws + 33718528);
  u16*  b3mb  = (u16*)(ws + 42148096);
  u16*  wcat  = (u16*)(ws + 47943424);
  u16*  w_qkvb = wcat;

  detect_kernel<<<1, 64, 0, stream>>>((const u16*)x, dflag);
  wconv_kernel<<<432, 256, 0, stream>>>(w_qkv, w_proj, w_fc1, w_fc2, wcat, dflag);
  b3m_kernel<<<dim3(343, 24), 256, 0, stream>>>(bias_tb, rel_idx, b3mb, dflag);
  // 1. LN1 + shift + window partition
  ln_gather_kernel<<<T_TOK / 4, 256, 0, stream>>>(x, g1, b1, winb, dflag);
  // 2. QKV GEMM -> planar qkv (q pre-scaled by log2e/sqrt(32))
  qkv_kernel<<<dim3(343, 3), 256, 0, stream>>>(winb, w_qkvb, b_qkv, qkvb, dflag);
  // 3. flash attention -> attnb
  attn_mfma_kernel<<<dim3(3, 384), 512, 0, stream>>>(qkvb, b3mb, attnb);
  // 4. proj + residual + LN2 + FC1 + GELU + FC2 + residual + scatter -> d_out
  mlp_fused_kernel<<<686, 256, 0, stream>>>(attnb, wcat, x, b_proj, g2, b2,
                                            b_fc1, b_fc2, d_out, dflag);
}